// Round 1
// baseline (703.450 us; speedup 1.0000x reference)
//
#include <hip/hip_runtime.h>
#include <hip/hip_bf16.h>

typedef unsigned short u16;
typedef unsigned int u32;
typedef __attribute__((ext_vector_type(8))) short bf16x8;
typedef __attribute__((ext_vector_type(4))) float f32x4;

typedef __attribute__((address_space(1))) const u32 as1_u32;
typedef __attribute__((address_space(3))) u32 as3_u32;

#define MFMA16(a, b, c) __builtin_amdgcn_mfma_f32_16x16x32_bf16(a, b, c, 0, 0, 0)

__device__ __forceinline__ void gld16(const void* g, void* l) {
  __builtin_amdgcn_global_load_lds((as1_u32*)g, (as3_u32*)l, 16, 0, 0);
}

__device__ __forceinline__ float b2f(u16 u) { return __uint_as_float(((u32)u) << 16); }
__device__ __forceinline__ u16 f2b(float f) {
  u32 x = __float_as_uint(f);
  u32 r = (x + 0x7fffu + ((x >> 16) & 1u)) >> 16;
  return (u16)r;
}

__device__ __forceinline__ float wave_red(float v) {
  for (int o = 32; o; o >>= 1) v += __shfl_down(v, o);
  return v;
}

// ---------------- cast f32 -> bf16 (n multiple of 1024) ----------------
__global__ __launch_bounds__(256) void cast_kernel(const float* __restrict__ in,
                                                   u16* __restrict__ out, int n) {
  int i = (blockIdx.x * 256 + threadIdx.x) * 4;
  float4 v = *reinterpret_cast<const float4*>(in + i);
  ushort4 o;
  o.x = f2b(v.x); o.y = f2b(v.y); o.z = f2b(v.z); o.w = f2b(v.w);
  *reinterpret_cast<ushort4*>(out + i) = o;
}

// ---------------- generic GEMM: C[m,n] = sum_k A[m,k]*W[n,k] (+bias) ----------------
// EPI: 0 = f32 out, 1 = bf16 out, 2 = gelu(exact) -> bf16 out
// BIASM: 0 = none, 1 = bias[col], 2 = bias[row]
template <int EPI, int BIASM>
__global__ __launch_bounds__(256) void gemm_bt(
    const u16* __restrict__ A, const u16* __restrict__ W, const float* __restrict__ bias,
    void* __restrict__ Cout, int M, int N, int K, int lda, int ldw, int ldc,
    long long bsA, long long bsW, long long bsC) {
  __shared__ u16 a_sm[128 * 32];
  __shared__ u16 b_sm[128 * 32];
  const int t = threadIdx.x;
  const int lane = t & 63;
  const int wv = t >> 6;
  const int wm = wv >> 1, wn = wv & 1;
  const int l15 = lane & 15, l4 = lane >> 4;
  const long long zb = blockIdx.z;

  const u16* Ab = A + zb * bsA;
  const u16* Wb = W + zb * bsW;

  const u16* ag = Ab + (size_t)(blockIdx.y * 128 + (t >> 2)) * lda + (t & 3) * 8;
  const u16* wg = Wb + (size_t)(blockIdx.x * 128 + (t >> 2)) * ldw + (t & 3) * 8;
  u16* ad = a_sm + t * 8;
  u16* bd = b_sm + t * 8;

  f32x4 acc[4][4] = {};

  for (int k0 = 0; k0 < K; k0 += 32) {
    gld16(ag, ad);
    gld16(ag + (size_t)64 * lda, ad + 64 * 32);
    gld16(wg, bd);
    gld16(wg + (size_t)64 * ldw, bd + 64 * 32);
    ag += 32; wg += 32;
    __syncthreads();
    bf16x8 af[4], bf[4];
#pragma unroll
    for (int m = 0; m < 4; m++)
      af[m] = *reinterpret_cast<const bf16x8*>(&a_sm[(wm * 64 + m * 16 + l15) * 32 + l4 * 8]);
#pragma unroll
    for (int n = 0; n < 4; n++)
      bf[n] = *reinterpret_cast<const bf16x8*>(&b_sm[(wn * 64 + n * 16 + l15) * 32 + l4 * 8]);
#pragma unroll
    for (int m = 0; m < 4; m++)
#pragma unroll
      for (int n = 0; n < 4; n++)
        acc[m][n] = MFMA16(af[m], bf[n], acc[m][n]);
    __syncthreads();
  }

  const int gm0 = blockIdx.y * 128 + wm * 64;
  const int gn0 = blockIdx.x * 128 + wn * 64;
  float* cf = reinterpret_cast<float*>(Cout) + zb * bsC;
  u16* cb = reinterpret_cast<u16*>(Cout) + zb * bsC;
#pragma unroll
  for (int m = 0; m < 4; m++) {
#pragma unroll
    for (int n = 0; n < 4; n++) {
      const int col = gn0 + n * 16 + l15;
      float bc = (BIASM == 1) ? bias[col] : 0.f;
#pragma unroll
      for (int r = 0; r < 4; r++) {
        const int row = gm0 + m * 16 + l4 * 4 + r;
        float v = acc[m][n][r];
        if (BIASM == 1) v += bc;
        if (BIASM == 2) v += bias[row];
        if (EPI == 2) v = 0.5f * v * (1.0f + erff(v * 0.70710678118654752f));
        if (EPI == 0) cf[(size_t)row * ldc + col] = v;
        else          cb[(size_t)row * ldc + col] = f2b(v);
      }
    }
  }
}

// ---------------- scores: probs = exp(QK^T/8) (masked->0), unnormalized, bf16 ----------------
// grid: (8 s-chunks of 256, 128 bh), block 256
__global__ __launch_bounds__(256) void scores_kernel(const u16* __restrict__ QH,
                                                     const u16* __restrict__ KH,
                                                     const int* __restrict__ mask,
                                                     u16* __restrict__ probs) {
  __shared__ u16 q_sm[64 * 64];
  __shared__ u16 k_sm[256 * 64];
  const int bh = blockIdx.y;
  const int b = bh >> 4, h = bh & 15;
  const int sc = blockIdx.x;
  const int t = threadIdx.x;
  const int lane = t & 63;
  const int wv = t >> 6;
  const int l15 = lane & 15, l4 = lane >> 4;

  {
    const u16* src = QH + (size_t)(b * 64 + (t >> 3)) * 1024 + h * 64 + (t & 7) * 8;
    u16* dst = q_sm + t * 8;
    gld16(src, dst);
    gld16(src + (size_t)32 * 1024, dst + 32 * 64);
  }
  {
    const u16* src = KH + (size_t)(b * 2048 + sc * 256 + (t >> 3)) * 1024 + h * 64 + (t & 7) * 8;
    u16* dst = k_sm + t * 8;
#pragma unroll
    for (int i = 0; i < 8; i++)
      gld16(src + (size_t)i * 32 * 1024, dst + i * 32 * 64);
  }
  __syncthreads();

  f32x4 acc[4][4] = {};
#pragma unroll
  for (int ks = 0; ks < 2; ks++) {
    bf16x8 af[4], bf[4];
#pragma unroll
    for (int m = 0; m < 4; m++)
      af[m] = *reinterpret_cast<const bf16x8*>(&q_sm[(m * 16 + l15) * 64 + ks * 32 + l4 * 8]);
#pragma unroll
    for (int n = 0; n < 4; n++)
      bf[n] = *reinterpret_cast<const bf16x8*>(&k_sm[(wv * 64 + n * 16 + l15) * 64 + ks * 32 + l4 * 8]);
#pragma unroll
    for (int m = 0; m < 4; m++)
#pragma unroll
      for (int n = 0; n < 4; n++)
        acc[m][n] = MFMA16(af[m], bf[n], acc[m][n]);
  }

#pragma unroll
  for (int n = 0; n < 4; n++) {
    const int sg = sc * 256 + wv * 64 + n * 16 + l15;
    const bool keep = mask[b * 2048 + sg] != 0;
#pragma unroll
    for (int m = 0; m < 4; m++) {
#pragma unroll
      for (int r = 0; r < 4; r++) {
        const int row = m * 16 + l4 * 4 + r;
        float p = keep ? __expf(acc[m][n][r] * 0.125f) : 0.f;
        probs[((size_t)bh * 64 + row) * 2048 + sg] = f2b(p);
      }
    }
  }
}

// ---------------- rowsum -> 1/sum ----------------
__global__ __launch_bounds__(256) void rowsum_kernel(const u16* __restrict__ probs,
                                                     float* __restrict__ inv) {
  __shared__ float red[4];
  const int row = blockIdx.x;
  const int t = threadIdx.x;
  uint4 r4 = *reinterpret_cast<const uint4*>(probs + (size_t)row * 2048 + t * 8);
  float s = b2f((u16)(r4.x & 0xffffu)) + b2f((u16)(r4.x >> 16)) +
            b2f((u16)(r4.y & 0xffffu)) + b2f((u16)(r4.y >> 16)) +
            b2f((u16)(r4.z & 0xffffu)) + b2f((u16)(r4.z >> 16)) +
            b2f((u16)(r4.w & 0xffffu)) + b2f((u16)(r4.w >> 16));
  s = wave_red(s);
  if ((t & 63) == 0) red[t >> 6] = s;
  __syncthreads();
  if (t == 0) inv[row] = 1.0f / (red[0] + red[1] + red[2] + red[3]);
}

// ---------------- PV: attn[b,l,h*64+hd] = (probs_row . VT_row) * inv ----------------
// grid: 128 (bh), block 256
__global__ __launch_bounds__(256) void pv_kernel(const u16* __restrict__ probs,
                                                 const u16* __restrict__ VT,
                                                 const float* __restrict__ inv,
                                                 u16* __restrict__ attn) {
  __shared__ u16 a_sm[64 * 64];
  __shared__ u16 b_sm[64 * 64];
  const int bh = blockIdx.x;
  const int b = bh >> 4, h = bh & 15;
  const u16* Ab = probs + (size_t)bh * 64 * 2048;
  const u16* Bb = VT + ((size_t)b * 1024 + h * 64) * 2048;
  const int t = threadIdx.x;
  const int lane = t & 63;
  const int wv = t >> 6;
  const int wm = wv >> 1, wn = wv & 1;
  const int l15 = lane & 15, l4 = lane >> 4;

  f32x4 acc[2][2] = {};
  for (int k0 = 0; k0 < 2048; k0 += 64) {
    const u16* as = Ab + (size_t)(t >> 3) * 2048 + k0 + (t & 7) * 8;
    const u16* bs = Bb + (size_t)(t >> 3) * 2048 + k0 + (t & 7) * 8;
    u16* ad = a_sm + t * 8;
    u16* bd = b_sm + t * 8;
    gld16(as, ad);
    gld16(as + (size_t)32 * 2048, ad + 32 * 64);
    gld16(bs, bd);
    gld16(bs + (size_t)32 * 2048, bd + 32 * 64);
    __syncthreads();
#pragma unroll
    for (int ks = 0; ks < 2; ks++) {
      bf16x8 af[2], bf[2];
#pragma unroll
      for (int m = 0; m < 2; m++)
        af[m] = *reinterpret_cast<const bf16x8*>(&a_sm[(wm * 32 + m * 16 + l15) * 64 + ks * 32 + l4 * 8]);
#pragma unroll
      for (int n = 0; n < 2; n++)
        bf[n] = *reinterpret_cast<const bf16x8*>(&b_sm[(wn * 32 + n * 16 + l15) * 64 + ks * 32 + l4 * 8]);
#pragma unroll
      for (int m = 0; m < 2; m++)
#pragma unroll
        for (int n = 0; n < 2; n++)
          acc[m][n] = MFMA16(af[m], bf[n], acc[m][n]);
    }
    __syncthreads();
  }

#pragma unroll
  for (int m = 0; m < 2; m++) {
#pragma unroll
    for (int n = 0; n < 2; n++) {
#pragma unroll
      for (int r = 0; r < 4; r++) {
        const int l = wm * 32 + m * 16 + l4 * 4 + r;
        const int hd = wn * 32 + n * 16 + l15;
        float v = acc[m][n][r] * inv[bh * 64 + l];
        attn[(size_t)(b * 64 + l) * 1024 + h * 64 + hd] = f2b(v);
      }
    }
  }
}

// ---------------- head-mean of normalized probs -> attn_weights [B,L,S] f32 ----------------
__global__ __launch_bounds__(256) void mean_kernel(const u16* __restrict__ probs,
                                                   const float* __restrict__ inv,
                                                   float* __restrict__ outw) {
  __shared__ float s_inv[16];
  const int bl = blockIdx.x;
  const int b = bl >> 6, l = bl & 63;
  const int t = threadIdx.x;
  if (t < 16) s_inv[t] = inv[(b * 16 + t) * 64 + l] * 0.0625f;
  __syncthreads();
  float av[8] = {0.f, 0.f, 0.f, 0.f, 0.f, 0.f, 0.f, 0.f};
  for (int h = 0; h < 16; h++) {
    uint4 r4 = *reinterpret_cast<const uint4*>(
        probs + ((size_t)((b * 16 + h) * 64 + l)) * 2048 + t * 8);
    float sc = s_inv[h];
    av[0] += b2f((u16)(r4.x & 0xffffu)) * sc; av[1] += b2f((u16)(r4.x >> 16)) * sc;
    av[2] += b2f((u16)(r4.y & 0xffffu)) * sc; av[3] += b2f((u16)(r4.y >> 16)) * sc;
    av[4] += b2f((u16)(r4.z & 0xffffu)) * sc; av[5] += b2f((u16)(r4.w >> 16)) * 0.f + b2f((u16)(r4.z >> 16)) * sc;
    av[6] += b2f((u16)(r4.w & 0xffffu)) * sc; av[7] += b2f((u16)(r4.w >> 16)) * sc;
  }
  float* o = outw + (size_t)bl * 2048 + t * 8;
  *reinterpret_cast<float4*>(o) = make_float4(av[0], av[1], av[2], av[3]);
  *reinterpret_cast<float4*>(o + 4) = make_float4(av[4], av[5], av[6], av[7]);
}

// ---------------- LayerNorm over D=1024: out = LN(a+b)*g+beta ----------------
__global__ __launch_bounds__(256) void ln_kernel(const float* __restrict__ a,
                                                 const float* __restrict__ b2,
                                                 const float* __restrict__ g,
                                                 const float* __restrict__ bet,
                                                 float* __restrict__ outf,
                                                 u16* __restrict__ outb) {
  __shared__ float red[8];
  __shared__ float mv[2];
  const int row = blockIdx.x;
  const int t = threadIdx.x;
  const float4 va = *reinterpret_cast<const float4*>(a + (size_t)row * 1024 + t * 4);
  const float4 vb = *reinterpret_cast<const float4*>(b2 + (size_t)row * 1024 + t * 4);
  float x0 = va.x + vb.x, x1 = va.y + vb.y, x2 = va.z + vb.z, x3 = va.w + vb.w;
  float s = x0 + x1 + x2 + x3;
  float q = x0 * x0 + x1 * x1 + x2 * x2 + x3 * x3;
  s = wave_red(s);
  q = wave_red(q);
  if ((t & 63) == 0) { red[t >> 6] = s; red[4 + (t >> 6)] = q; }
  __syncthreads();
  if (t == 0) {
    float S = red[0] + red[1] + red[2] + red[3];
    float Q = red[4] + red[5] + red[6] + red[7];
    float mu = S * (1.f / 1024.f);
    float var = Q * (1.f / 1024.f) - mu * mu;
    mv[0] = mu;
    mv[1] = rsqrtf(var + 1e-5f);
  }
  __syncthreads();
  const float mu = mv[0], rs = mv[1];
  const float4 vg = *reinterpret_cast<const float4*>(g + t * 4);
  const float4 ve = *reinterpret_cast<const float4*>(bet + t * 4);
  float y0 = (x0 - mu) * rs * vg.x + ve.x;
  float y1 = (x1 - mu) * rs * vg.y + ve.y;
  float y2 = (x2 - mu) * rs * vg.z + ve.z;
  float y3 = (x3 - mu) * rs * vg.w + ve.w;
  *reinterpret_cast<float4*>(outf + (size_t)row * 1024 + t * 4) = make_float4(y0, y1, y2, y3);
  if (outb) {
    ushort4 o;
    o.x = f2b(y0); o.y = f2b(y1); o.z = f2b(y2); o.w = f2b(y3);
    *reinterpret_cast<ushort4*>(outb + (size_t)row * 1024 + t * 4) = o;
  }
}

extern "C" void kernel_launch(void* const* d_in, const int* in_sizes, int n_in,
                              void* d_out, int out_size, void* d_ws, size_t ws_size,
                              hipStream_t stream) {
  const float* latents = (const float*)d_in[0];
  const float* context = (const float*)d_in[1];
  const int* cmask = (const int*)d_in[2];
  const float* q_w = (const float*)d_in[3];   const float* q_b = (const float*)d_in[4];
  const float* k_w = (const float*)d_in[5];   const float* k_b = (const float*)d_in[6];
  const float* v_w = (const float*)d_in[7];   const float* v_b = (const float*)d_in[8];
  const float* in_wq = (const float*)d_in[9]; const float* in_bq = (const float*)d_in[10];
  const float* in_wk = (const float*)d_in[11]; const float* in_bk = (const float*)d_in[12];
  const float* in_wv = (const float*)d_in[13]; const float* in_bv = (const float*)d_in[14];
  const float* out_w = (const float*)d_in[15]; const float* out_b = (const float*)d_in[16];
  const float* ln1_g = (const float*)d_in[17]; const float* ln1_b = (const float*)d_in[18];
  const float* ln2_g = (const float*)d_in[19]; const float* ln2_b = (const float*)d_in[20];
  const float* ff_w1 = (const float*)d_in[21]; const float* ff_b1 = (const float*)d_in[22];
  const float* ff_w2 = (const float*)d_in[23]; const float* ff_b2 = (const float*)d_in[24];

  char* wsb = (char*)d_ws;
  size_t off = 0;
  auto alloc = [&](size_t bytes) -> char* {
    char* p = wsb + off;
    off = (off + bytes + 255) & ~(size_t)255;
    return p;
  };

  u16* ctx_b = (u16*)alloc(16384LL * 1024 * 2);  // reused as VT after ctx is dead
  u16* k1    = (u16*)alloc(16384LL * 1024 * 2);  // reused as V1 after KH is built
  u16* kh    = (u16*)alloc(16384LL * 1024 * 2);
  u16* probs = (u16*)alloc((size_t)8 * 16 * 64 * 2048 * 2);
  u16* wqb  = (u16*)alloc(1048576LL * 2);
  u16* wkb  = (u16*)alloc(1048576LL * 2);
  u16* wvb  = (u16*)alloc(1048576LL * 2);
  u16* wiqb = (u16*)alloc(1048576LL * 2);
  u16* wikb = (u16*)alloc(1048576LL * 2);
  u16* wivb = (u16*)alloc(1048576LL * 2);
  u16* wob  = (u16*)alloc(1048576LL * 2);
  u16* wf1b = (u16*)alloc(4194304LL * 2);
  u16* wf2b = (u16*)alloc(4194304LL * 2);
  u16* lat_b = (u16*)alloc(524288LL * 2);
  u16* q1    = (u16*)alloc(524288LL * 2);
  u16* qhb   = (u16*)alloc(524288LL * 2);
  u16* attn_b = (u16*)alloc(524288LL * 2);
  float* inv_rs = (float*)alloc(8192LL * 4);
  float* ao = (float*)alloc(524288LL * 4);
  float* xf = (float*)alloc(524288LL * 4);
  u16* xb = (u16*)alloc(524288LL * 2);
  u16* h1 = (u16*)alloc((size_t)512 * 4096 * 2);
  float* fo = (float*)alloc(524288LL * 4);

  // casts
  cast_kernel<<<dim3(16384), dim3(256), 0, stream>>>(context, ctx_b, 16777216);
  cast_kernel<<<dim3(512), dim3(256), 0, stream>>>(latents, lat_b, 524288);
  cast_kernel<<<dim3(1024), dim3(256), 0, stream>>>(q_w, wqb, 1048576);
  cast_kernel<<<dim3(1024), dim3(256), 0, stream>>>(k_w, wkb, 1048576);
  cast_kernel<<<dim3(1024), dim3(256), 0, stream>>>(v_w, wvb, 1048576);
  cast_kernel<<<dim3(1024), dim3(256), 0, stream>>>(in_wq, wiqb, 1048576);
  cast_kernel<<<dim3(1024), dim3(256), 0, stream>>>(in_wk, wikb, 1048576);
  cast_kernel<<<dim3(1024), dim3(256), 0, stream>>>(in_wv, wivb, 1048576);
  cast_kernel<<<dim3(1024), dim3(256), 0, stream>>>(out_w, wob, 1048576);
  cast_kernel<<<dim3(4096), dim3(256), 0, stream>>>(ff_w1, wf1b, 4194304);
  cast_kernel<<<dim3(4096), dim3(256), 0, stream>>>(ff_w2, wf2b, 4194304);

  // K chain: K1 = ctx*k_w^T + k_b ; KH = K1*in_wk^T + in_bk
  gemm_bt<1, 1><<<dim3(8, 128, 1), 256, 0, stream>>>(ctx_b, wkb, k_b, k1,
      16384, 1024, 1024, 1024, 1024, 1024, 0, 0, 0);
  gemm_bt<1, 1><<<dim3(8, 128, 1), 256, 0, stream>>>(k1, wikb, in_bk, kh,
      16384, 1024, 1024, 1024, 1024, 1024, 0, 0, 0);
  // V chain: V1 = ctx*v_w^T + v_b (into k1 buffer) ; VT[b][d][s] = in_wv . V1 + in_bv (into ctx buffer)
  gemm_bt<1, 1><<<dim3(8, 128, 1), 256, 0, stream>>>(ctx_b, wvb, v_b, k1,
      16384, 1024, 1024, 1024, 1024, 1024, 0, 0, 0);
  gemm_bt<1, 2><<<dim3(16, 8, 8), 256, 0, stream>>>(wivb, k1, in_bv, ctx_b,
      1024, 2048, 1024, 1024, 1024, 2048, 0, 2048LL * 1024, 1024LL * 2048);
  // Q chain
  gemm_bt<1, 1><<<dim3(8, 4, 1), 256, 0, stream>>>(lat_b, wqb, q_b, q1,
      512, 1024, 1024, 1024, 1024, 1024, 0, 0, 0);
  gemm_bt<1, 1><<<dim3(8, 4, 1), 256, 0, stream>>>(q1, wiqb, in_bq, qhb,
      512, 1024, 1024, 1024, 1024, 1024, 0, 0, 0);

  // attention
  scores_kernel<<<dim3(8, 128), 256, 0, stream>>>(qhb, kh, cmask, probs);
  rowsum_kernel<<<dim3(8192), 256, 0, stream>>>(probs, inv_rs);
  pv_kernel<<<dim3(128), 256, 0, stream>>>(probs, ctx_b /*VT*/, inv_rs, attn_b);
  mean_kernel<<<dim3(512), 256, 0, stream>>>(probs, inv_rs, (float*)d_out + 524288);

  // out projection + LN1
  gemm_bt<0, 1><<<dim3(8, 4, 1), 256, 0, stream>>>(attn_b, wob, out_b, ao,
      512, 1024, 1024, 1024, 1024, 1024, 0, 0, 0);
  ln_kernel<<<dim3(512), 256, 0, stream>>>(latents, ao, ln1_g, ln1_b, xf, xb);

  // FF
  gemm_bt<2, 1><<<dim3(32, 4, 1), 256, 0, stream>>>(xb, wf1b, ff_b1, h1,
      512, 4096, 1024, 1024, 1024, 4096, 0, 0, 0);
  gemm_bt<0, 1><<<dim3(8, 4, 1), 256, 0, stream>>>(h1, wf2b, ff_b2, fo,
      512, 1024, 4096, 4096, 4096, 1024, 0, 0, 0);
  ln_kernel<<<dim3(512), 256, 0, stream>>>(xf, fo, ln2_g, ln2_b, (float*)d_out, nullptr);
}

// Round 2
// 512.734 us; speedup vs baseline: 1.3720x; 1.3720x over previous
//
#include <hip/hip_runtime.h>
#include <hip/hip_bf16.h>

typedef unsigned short u16;
typedef unsigned int u32;
typedef __attribute__((ext_vector_type(8))) short bf16x8;
typedef __attribute__((ext_vector_type(4))) float f32x4;

typedef __attribute__((address_space(1))) const u32 as1_u32;
typedef __attribute__((address_space(3))) u32 as3_u32;

#define MFMA16(a, b, c) __builtin_amdgcn_mfma_f32_16x16x32_bf16(a, b, c, 0, 0, 0)

__device__ __forceinline__ void gld16(const void* g, void* l) {
  __builtin_amdgcn_global_load_lds((as1_u32*)g, (as3_u32*)l, 16, 0, 0);
}

__device__ __forceinline__ float b2f(u16 u) { return __uint_as_float(((u32)u) << 16); }
__device__ __forceinline__ u16 f2b(float f) {
  u32 x = __float_as_uint(f);
  u32 r = (x + 0x7fffu + ((x >> 16) & 1u)) >> 16;
  return (u16)r;
}

__device__ __forceinline__ float wave_red(float v) {
  for (int o = 32; o; o >>= 1) v += __shfl_down(v, o);
  return v;
}

// ---------------- fused segmented cast f32 -> bf16 ----------------
// 8 segments, all boundaries multiples of 1024 elems; each block does 1024 elems.
__global__ __launch_bounds__(256) void fused_cast_kernel(
    const float* __restrict__ s0, const float* __restrict__ s1,
    const float* __restrict__ s2, const float* __restrict__ s3,
    const float* __restrict__ s4, const float* __restrict__ s5,
    const float* __restrict__ s6, const float* __restrict__ s7,
    u16* __restrict__ d0, u16* __restrict__ d1, u16* __restrict__ d2,
    u16* __restrict__ d3, u16* __restrict__ d4, u16* __restrict__ d5,
    u16* __restrict__ d6, u16* __restrict__ d7) {
  const unsigned base = blockIdx.x * 1024u;
  const float* src;
  u16* dst;
  unsigned off;
  if (base < 16777216u)      { src = s0; dst = d0; off = 0u; }
  else if (base < 17301504u) { src = s1; dst = d1; off = 16777216u; }
  else if (base < 18350080u) { src = s2; dst = d2; off = 17301504u; }
  else if (base < 19398656u) { src = s3; dst = d3; off = 18350080u; }
  else if (base < 20447232u) { src = s4; dst = d4; off = 19398656u; }
  else if (base < 21495808u) { src = s5; dst = d5; off = 20447232u; }
  else if (base < 25690112u) { src = s6; dst = d6; off = 21495808u; }
  else                       { src = s7; dst = d7; off = 25690112u; }
  const unsigned i = base - off + threadIdx.x * 4u;
  float4 v = *reinterpret_cast<const float4*>(src + i);
  ushort4 o;
  o.x = f2b(v.x); o.y = f2b(v.y); o.z = f2b(v.z); o.w = f2b(v.w);
  *reinterpret_cast<ushort4*>(dst + i) = o;
}

// ---------------- cast + transpose: out[i][j] = bf16(in[j][i]), 1024x1024 ----------------
__global__ __launch_bounds__(256) void castT_kernel(const float* __restrict__ in,
                                                    u16* __restrict__ out) {
  __shared__ u16 sm[32][33];
  const int r0 = blockIdx.y * 32, c0 = blockIdx.x * 32;
  const int t = threadIdx.x;
  const int r = t >> 3, c4 = (t & 7) * 4;
  float4 v = *reinterpret_cast<const float4*>(in + (size_t)(r0 + r) * 1024 + c0 + c4);
  sm[c4 + 0][r] = f2b(v.x);
  sm[c4 + 1][r] = f2b(v.y);
  sm[c4 + 2][r] = f2b(v.z);
  sm[c4 + 3][r] = f2b(v.w);
  __syncthreads();
  ushort4 o;
  o.x = sm[r][c4 + 0]; o.y = sm[r][c4 + 1]; o.z = sm[r][c4 + 2]; o.w = sm[r][c4 + 3];
  *reinterpret_cast<ushort4*>(out + (size_t)(c0 + r) * 1024 + r0 + c4) = o;
}

// ---------------- bias compose: out[o] = dot(A[o,:1024], b) + b2[o] ----------------
__global__ __launch_bounds__(256) void biascomp_kernel(const float* __restrict__ A,
                                                       const float* __restrict__ b,
                                                       const float* __restrict__ b2,
                                                       float* __restrict__ out) {
  __shared__ float red[4];
  const int row = blockIdx.x;
  const int t = threadIdx.x;
  float4 va = *reinterpret_cast<const float4*>(A + (size_t)row * 1024 + t * 4);
  float4 vb = *reinterpret_cast<const float4*>(b + t * 4);
  float s = va.x * vb.x + va.y * vb.y + va.z * vb.z + va.w * vb.w;
  s = wave_red(s);
  if ((t & 63) == 0) red[t >> 6] = s;
  __syncthreads();
  if (t == 0) out[row] = red[0] + red[1] + red[2] + red[3] + b2[row];
}

// ---------------- 128x128 GEMM: C[m,n] = sum_k A[m,k]*W[n,k] (+bias) ----------------
// EPI: 0 = f32 out, 1 = bf16 out, 2 = gelu(exact) -> bf16 out
// BIASM: 0 = none, 1 = bias[col], 2 = bias[row]
template <int EPI, int BIASM>
__global__ __launch_bounds__(256) void gemm_bt(
    const u16* __restrict__ A, const u16* __restrict__ W, const float* __restrict__ bias,
    void* __restrict__ Cout, int M, int N, int K, int lda, int ldw, int ldc,
    long long bsA, long long bsW, long long bsC) {
  __shared__ u16 a_sm[128 * 32];
  __shared__ u16 b_sm[128 * 32];
  const int t = threadIdx.x;
  const int lane = t & 63;
  const int wv = t >> 6;
  const int wm = wv >> 1, wn = wv & 1;
  const int l15 = lane & 15, l4 = lane >> 4;
  const long long zb = blockIdx.z;

  const u16* Ab = A + zb * bsA;
  const u16* Wb = W + zb * bsW;

  const u16* ag = Ab + (size_t)(blockIdx.y * 128 + (t >> 2)) * lda + (t & 3) * 8;
  const u16* wg = Wb + (size_t)(blockIdx.x * 128 + (t >> 2)) * ldw + (t & 3) * 8;
  u16* ad = a_sm + t * 8;
  u16* bd = b_sm + t * 8;

  f32x4 acc[4][4] = {};

  for (int k0 = 0; k0 < K; k0 += 32) {
    gld16(ag, ad);
    gld16(ag + (size_t)64 * lda, ad + 64 * 32);
    gld16(wg, bd);
    gld16(wg + (size_t)64 * ldw, bd + 64 * 32);
    ag += 32; wg += 32;
    __syncthreads();
    bf16x8 af[4], bf[4];
#pragma unroll
    for (int m = 0; m < 4; m++)
      af[m] = *reinterpret_cast<const bf16x8*>(&a_sm[(wm * 64 + m * 16 + l15) * 32 + l4 * 8]);
#pragma unroll
    for (int n = 0; n < 4; n++)
      bf[n] = *reinterpret_cast<const bf16x8*>(&b_sm[(wn * 64 + n * 16 + l15) * 32 + l4 * 8]);
#pragma unroll
    for (int m = 0; m < 4; m++)
#pragma unroll
      for (int n = 0; n < 4; n++)
        acc[m][n] = MFMA16(af[m], bf[n], acc[m][n]);
    __syncthreads();
  }

  const int gm0 = blockIdx.y * 128 + wm * 64;
  const int gn0 = blockIdx.x * 128 + wn * 64;
  float* cf = reinterpret_cast<float*>(Cout) + zb * bsC;
  u16* cb = reinterpret_cast<u16*>(Cout) + zb * bsC;
#pragma unroll
  for (int m = 0; m < 4; m++) {
#pragma unroll
    for (int n = 0; n < 4; n++) {
      const int col = gn0 + n * 16 + l15;
      float bc = (BIASM == 1) ? bias[col] : 0.f;
#pragma unroll
      for (int r = 0; r < 4; r++) {
        const int row = gm0 + m * 16 + l4 * 4 + r;
        float v = acc[m][n][r];
        if (BIASM == 1) v += bc;
        if (BIASM == 2) v += bias[row];
        if (EPI == 2) v = 0.5f * v * (1.0f + erff(v * 0.70710678118654752f));
        if (EPI == 0) cf[(size_t)row * ldc + col] = v;
        else          cb[(size_t)row * ldc + col] = f2b(v);
      }
    }
  }
}

// ---------------- 64x64 GEMM (high-parallelism small-shape variant) ----------------
template <int EPI, int BIASM>
__global__ __launch_bounds__(256) void gemm64(
    const u16* __restrict__ A, const u16* __restrict__ W, const float* __restrict__ bias,
    void* __restrict__ Cout, int M, int N, int K, int lda, int ldw, int ldc) {
  __shared__ u16 a_sm[64 * 32];
  __shared__ u16 b_sm[64 * 32];
  const int t = threadIdx.x;
  const int lane = t & 63;
  const int wv = t >> 6;
  const int wm = wv >> 1, wn = wv & 1;
  const int l15 = lane & 15, l4 = lane >> 4;

  const u16* ag = A + (size_t)(blockIdx.y * 64 + (t >> 2)) * lda + (t & 3) * 8;
  const u16* wg = W + (size_t)(blockIdx.x * 64 + (t >> 2)) * ldw + (t & 3) * 8;
  u16* ad = a_sm + t * 8;
  u16* bd = b_sm + t * 8;

  f32x4 acc[2][2] = {};

  for (int k0 = 0; k0 < K; k0 += 32) {
    gld16(ag, ad);
    gld16(wg, bd);
    ag += 32; wg += 32;
    __syncthreads();
    bf16x8 af[2], bf[2];
#pragma unroll
    for (int m = 0; m < 2; m++)
      af[m] = *reinterpret_cast<const bf16x8*>(&a_sm[(wm * 32 + m * 16 + l15) * 32 + l4 * 8]);
#pragma unroll
    for (int n = 0; n < 2; n++)
      bf[n] = *reinterpret_cast<const bf16x8*>(&b_sm[(wn * 32 + n * 16 + l15) * 32 + l4 * 8]);
#pragma unroll
    for (int m = 0; m < 2; m++)
#pragma unroll
      for (int n = 0; n < 2; n++)
        acc[m][n] = MFMA16(af[m], bf[n], acc[m][n]);
    __syncthreads();
  }

  const int gm0 = blockIdx.y * 64 + wm * 32;
  const int gn0 = blockIdx.x * 64 + wn * 32;
  float* cf = reinterpret_cast<float*>(Cout);
  u16* cb = reinterpret_cast<u16*>(Cout);
#pragma unroll
  for (int m = 0; m < 2; m++) {
#pragma unroll
    for (int n = 0; n < 2; n++) {
      const int col = gn0 + n * 16 + l15;
      float bc = (BIASM == 1) ? bias[col] : 0.f;
#pragma unroll
      for (int r = 0; r < 4; r++) {
        const int row = gm0 + m * 16 + l4 * 4 + r;
        float v = acc[m][n][r];
        if (BIASM == 1) v += bc;
        if (BIASM == 2) v += bias[row];
        if (EPI == 2) v = 0.5f * v * (1.0f + erff(v * 0.70710678118654752f));
        if (EPI == 0) cf[(size_t)row * ldc + col] = v;
        else          cb[(size_t)row * ldc + col] = f2b(v);
      }
    }
  }
}

// ---------------- scores: probs = exp(QK^T/8) (masked->0), unnormalized, bf16 ----------------
__global__ __launch_bounds__(256) void scores_kernel(const u16* __restrict__ QH,
                                                     const u16* __restrict__ KH,
                                                     const int* __restrict__ mask,
                                                     u16* __restrict__ probs) {
  __shared__ u16 q_sm[64 * 64];
  __shared__ u16 k_sm[256 * 64];
  const int bh = blockIdx.y;
  const int b = bh >> 4, h = bh & 15;
  const int sc = blockIdx.x;
  const int t = threadIdx.x;
  const int lane = t & 63;
  const int wv = t >> 6;
  const int l15 = lane & 15, l4 = lane >> 4;

  {
    const u16* src = QH + (size_t)(b * 64 + (t >> 3)) * 1024 + h * 64 + (t & 7) * 8;
    u16* dst = q_sm + t * 8;
    gld16(src, dst);
    gld16(src + (size_t)32 * 1024, dst + 32 * 64);
  }
  {
    const u16* src = KH + (size_t)(b * 2048 + sc * 256 + (t >> 3)) * 1024 + h * 64 + (t & 7) * 8;
    u16* dst = k_sm + t * 8;
#pragma unroll
    for (int i = 0; i < 8; i++)
      gld16(src + (size_t)i * 32 * 1024, dst + i * 32 * 64);
  }
  __syncthreads();

  f32x4 acc[4][4] = {};
#pragma unroll
  for (int ks = 0; ks < 2; ks++) {
    bf16x8 af[4], bf[4];
#pragma unroll
    for (int m = 0; m < 4; m++)
      af[m] = *reinterpret_cast<const bf16x8*>(&q_sm[(m * 16 + l15) * 64 + ks * 32 + l4 * 8]);
#pragma unroll
    for (int n = 0; n < 4; n++)
      bf[n] = *reinterpret_cast<const bf16x8*>(&k_sm[(wv * 64 + n * 16 + l15) * 64 + ks * 32 + l4 * 8]);
#pragma unroll
    for (int m = 0; m < 4; m++)
#pragma unroll
      for (int n = 0; n < 4; n++)
        acc[m][n] = MFMA16(af[m], bf[n], acc[m][n]);
  }

#pragma unroll
  for (int n = 0; n < 4; n++) {
    const int sg = sc * 256 + wv * 64 + n * 16 + l15;
    const bool keep = mask[b * 2048 + sg] != 0;
#pragma unroll
    for (int m = 0; m < 4; m++) {
#pragma unroll
      for (int r = 0; r < 4; r++) {
        const int row = m * 16 + l4 * 4 + r;
        float p = keep ? __expf(acc[m][n][r] * 0.125f) : 0.f;
        probs[((size_t)bh * 64 + row) * 2048 + sg] = f2b(p);
      }
    }
  }
}

// ---------------- rowsum -> 1/sum ----------------
__global__ __launch_bounds__(256) void rowsum_kernel(const u16* __restrict__ probs,
                                                     float* __restrict__ inv) {
  __shared__ float red[4];
  const int row = blockIdx.x;
  const int t = threadIdx.x;
  uint4 r4 = *reinterpret_cast<const uint4*>(probs + (size_t)row * 2048 + t * 8);
  float s = b2f((u16)(r4.x & 0xffffu)) + b2f((u16)(r4.x >> 16)) +
            b2f((u16)(r4.y & 0xffffu)) + b2f((u16)(r4.y >> 16)) +
            b2f((u16)(r4.z & 0xffffu)) + b2f((u16)(r4.z >> 16)) +
            b2f((u16)(r4.w & 0xffffu)) + b2f((u16)(r4.w >> 16));
  s = wave_red(s);
  if ((t & 63) == 0) red[t >> 6] = s;
  __syncthreads();
  if (t == 0) inv[row] = 1.0f / (red[0] + red[1] + red[2] + red[3]);
}

// ---------------- PV split-K partials: part[bh][c][l*64+hd] (f32, unnormalized) ----------------
__global__ __launch_bounds__(256) void pv_part_kernel(const u16* __restrict__ probs,
                                                      const u16* __restrict__ VT,
                                                      float* __restrict__ part) {
  __shared__ u16 a_sm[64 * 64];
  __shared__ u16 b_sm[64 * 64];
  const int c = blockIdx.x;
  const int bh = blockIdx.y;
  const int b = bh >> 4, h = bh & 15;
  const u16* Ab = probs + (size_t)bh * 64 * 2048;
  const u16* Bb = VT + ((size_t)b * 1024 + h * 64) * 2048;
  const int t = threadIdx.x;
  const int lane = t & 63;
  const int wv = t >> 6;
  const int wm = wv >> 1, wn = wv & 1;
  const int l15 = lane & 15, l4 = lane >> 4;

  f32x4 acc[2][2] = {};
  for (int k0 = c * 512; k0 < c * 512 + 512; k0 += 64) {
    const u16* as = Ab + (size_t)(t >> 3) * 2048 + k0 + (t & 7) * 8;
    const u16* bs = Bb + (size_t)(t >> 3) * 2048 + k0 + (t & 7) * 8;
    u16* ad = a_sm + t * 8;
    u16* bd = b_sm + t * 8;
    gld16(as, ad);
    gld16(as + (size_t)32 * 2048, ad + 32 * 64);
    gld16(bs, bd);
    gld16(bs + (size_t)32 * 2048, bd + 32 * 64);
    __syncthreads();
#pragma unroll
    for (int ks = 0; ks < 2; ks++) {
      bf16x8 af[2], bf[2];
#pragma unroll
      for (int m = 0; m < 2; m++)
        af[m] = *reinterpret_cast<const bf16x8*>(&a_sm[(wm * 32 + m * 16 + l15) * 64 + ks * 32 + l4 * 8]);
#pragma unroll
      for (int n = 0; n < 2; n++)
        bf[n] = *reinterpret_cast<const bf16x8*>(&b_sm[(wn * 32 + n * 16 + l15) * 64 + ks * 32 + l4 * 8]);
#pragma unroll
      for (int m = 0; m < 2; m++)
#pragma unroll
        for (int n = 0; n < 2; n++)
          acc[m][n] = MFMA16(af[m], bf[n], acc[m][n]);
    }
    __syncthreads();
  }

  float* po = part + ((size_t)(bh * 4 + c)) * 4096;
#pragma unroll
  for (int m = 0; m < 2; m++) {
#pragma unroll
    for (int n = 0; n < 2; n++) {
#pragma unroll
      for (int r = 0; r < 4; r++) {
        const int l = wm * 32 + m * 16 + l4 * 4 + r;
        const int hd = wn * 32 + n * 16 + l15;
        po[l * 64 + hd] = acc[m][n][r];
      }
    }
  }
}

// ---------------- PV reduce: attn = (sum_c part) * inv ----------------
__global__ __launch_bounds__(256) void pv_reduce_kernel(const float* __restrict__ part,
                                                        const float* __restrict__ inv,
                                                        u16* __restrict__ attn) {
  const int t = threadIdx.x;
  const int e0 = (blockIdx.x * 256 + t) * 4;
  const int bh = e0 >> 12;
  const int r = e0 & 4095;
  const int l = r >> 6, hd = r & 63;
  const int b = bh >> 4, h = bh & 15;
  const float* p = part + ((size_t)bh * 4) * 4096 + r;
  float4 v0 = *reinterpret_cast<const float4*>(p);
  float4 v1 = *reinterpret_cast<const float4*>(p + 4096);
  float4 v2 = *reinterpret_cast<const float4*>(p + 8192);
  float4 v3 = *reinterpret_cast<const float4*>(p + 12288);
  const float sc = inv[bh * 64 + l];
  ushort4 o;
  o.x = f2b((v0.x + v1.x + v2.x + v3.x) * sc);
  o.y = f2b((v0.y + v1.y + v2.y + v3.y) * sc);
  o.z = f2b((v0.z + v1.z + v2.z + v3.z) * sc);
  o.w = f2b((v0.w + v1.w + v2.w + v3.w) * sc);
  *reinterpret_cast<ushort4*>(attn + (size_t)(b * 64 + l) * 1024 + h * 64 + hd) = o;
}

// ---------------- head-mean of normalized probs -> attn_weights [B,L,S] f32 ----------------
__global__ __launch_bounds__(256) void mean_kernel(const u16* __restrict__ probs,
                                                   const float* __restrict__ inv,
                                                   float* __restrict__ outw) {
  __shared__ float s_inv[16];
  const int bl = blockIdx.x;
  const int b = bl >> 6, l = bl & 63;
  const int t = threadIdx.x;
  if (t < 16) s_inv[t] = inv[(b * 16 + t) * 64 + l] * 0.0625f;
  __syncthreads();
  float av[8] = {0.f, 0.f, 0.f, 0.f, 0.f, 0.f, 0.f, 0.f};
  for (int h = 0; h < 16; h++) {
    uint4 r4 = *reinterpret_cast<const uint4*>(
        probs + ((size_t)((b * 16 + h) * 64 + l)) * 2048 + t * 8);
    float sc = s_inv[h];
    av[0] += b2f((u16)(r4.x & 0xffffu)) * sc; av[1] += b2f((u16)(r4.x >> 16)) * sc;
    av[2] += b2f((u16)(r4.y & 0xffffu)) * sc; av[3] += b2f((u16)(r4.y >> 16)) * sc;
    av[4] += b2f((u16)(r4.z & 0xffffu)) * sc; av[5] += b2f((u16)(r4.z >> 16)) * sc;
    av[6] += b2f((u16)(r4.w & 0xffffu)) * sc; av[7] += b2f((u16)(r4.w >> 16)) * sc;
  }
  float* o = outw + (size_t)bl * 2048 + t * 8;
  *reinterpret_cast<float4*>(o) = make_float4(av[0], av[1], av[2], av[3]);
  *reinterpret_cast<float4*>(o + 4) = make_float4(av[4], av[5], av[6], av[7]);
}

// ---------------- LayerNorm over D=1024: out = LN(a+b)*g+beta ----------------
__global__ __launch_bounds__(256) void ln_kernel(const float* __restrict__ a,
                                                 const float* __restrict__ b2,
                                                 const float* __restrict__ g,
                                                 const float* __restrict__ bet,
                                                 float* __restrict__ outf,
                                                 u16* __restrict__ outb) {
  __shared__ float red[8];
  __shared__ float mv[2];
  const int row = blockIdx.x;
  const int t = threadIdx.x;
  const float4 va = *reinterpret_cast<const float4*>(a + (size_t)row * 1024 + t * 4);
  const float4 vb = *reinterpret_cast<const float4*>(b2 + (size_t)row * 1024 + t * 4);
  float x0 = va.x + vb.x, x1 = va.y + vb.y, x2 = va.z + vb.z, x3 = va.w + vb.w;
  float s = x0 + x1 + x2 + x3;
  float q = x0 * x0 + x1 * x1 + x2 * x2 + x3 * x3;
  s = wave_red(s);
  q = wave_red(q);
  if ((t & 63) == 0) { red[t >> 6] = s; red[4 + (t >> 6)] = q; }
  __syncthreads();
  if (t == 0) {
    float S = red[0] + red[1] + red[2] + red[3];
    float Q = red[4] + red[5] + red[6] + red[7];
    float mu = S * (1.f / 1024.f);
    float var = Q * (1.f / 1024.f) - mu * mu;
    mv[0] = mu;
    mv[1] = rsqrtf(var + 1e-5f);
  }
  __syncthreads();
  const float mu = mv[0], rs = mv[1];
  const float4 vg = *reinterpret_cast<const float4*>(g + t * 4);
  const float4 ve = *reinterpret_cast<const float4*>(bet + t * 4);
  float y0 = (x0 - mu) * rs * vg.x + ve.x;
  float y1 = (x1 - mu) * rs * vg.y + ve.y;
  float y2 = (x2 - mu) * rs * vg.z + ve.z;
  float y3 = (x3 - mu) * rs * vg.w + ve.w;
  *reinterpret_cast<float4*>(outf + (size_t)row * 1024 + t * 4) = make_float4(y0, y1, y2, y3);
  if (outb) {
    ushort4 o;
    o.x = f2b(y0); o.y = f2b(y1); o.z = f2b(y2); o.w = f2b(y3);
    *reinterpret_cast<ushort4*>(outb + (size_t)row * 1024 + t * 4) = o;
  }
}

extern "C" void kernel_launch(void* const* d_in, const int* in_sizes, int n_in,
                              void* d_out, int out_size, void* d_ws, size_t ws_size,
                              hipStream_t stream) {
  const float* latents = (const float*)d_in[0];
  const float* context = (const float*)d_in[1];
  const int* cmask = (const int*)d_in[2];
  const float* q_w = (const float*)d_in[3];   const float* q_b = (const float*)d_in[4];
  const float* k_w = (const float*)d_in[5];   const float* k_b = (const float*)d_in[6];
  const float* v_w = (const float*)d_in[7];   const float* v_b = (const float*)d_in[8];
  const float* in_wq = (const float*)d_in[9]; const float* in_bq = (const float*)d_in[10];
  const float* in_wk = (const float*)d_in[11]; const float* in_bk = (const float*)d_in[12];
  const float* in_wv = (const float*)d_in[13]; const float* in_bv = (const float*)d_in[14];
  const float* out_w = (const float*)d_in[15]; const float* out_b = (const float*)d_in[16];
  const float* ln1_g = (const float*)d_in[17]; const float* ln1_b = (const float*)d_in[18];
  const float* ln2_g = (const float*)d_in[19]; const float* ln2_b = (const float*)d_in[20];
  const float* ff_w1 = (const float*)d_in[21]; const float* ff_b1 = (const float*)d_in[22];
  const float* ff_w2 = (const float*)d_in[23]; const float* ff_b2 = (const float*)d_in[24];

  char* wsb = (char*)d_ws;
  size_t off = 0;
  auto alloc = [&](size_t bytes) -> char* {
    char* p = wsb + off;
    off = (off + bytes + 255) & ~(size_t)255;
    return p;
  };

  u16* ctx_b = (u16*)alloc(33554432);   // [16384,1024] bf16; region reused after VT
  u16* kh    = (u16*)alloc(33554432);   // [16384,1024] bf16 (KH)
  u16* vt    = (u16*)alloc(33554432);   // [8][1024][2048] bf16 (V^T per batch)
  u16* probs = (u16*)alloc(33554432);   // [128][64][2048] bf16
  float* pvp = (float*)alloc(8388608);  // [128][4][4096] f32 PV partials
  u16* lat_b = (u16*)alloc(1048576);
  u16* wiq   = (u16*)alloc(2097152);
  u16* wik   = (u16*)alloc(2097152);
  u16* wiv   = (u16*)alloc(2097152);
  u16* qwT   = (u16*)alloc(2097152);
  u16* kwT   = (u16*)alloc(2097152);
  u16* vwT   = (u16*)alloc(2097152);
  u16* wqc   = (u16*)alloc(2097152);
  u16* wkc   = (u16*)alloc(2097152);
  u16* wvc   = (u16*)alloc(2097152);
  u16* wob   = (u16*)alloc(2097152);
  u16* wf1b  = (u16*)alloc(8388608);
  u16* wf2b  = (u16*)alloc(8388608);
  float* b_qc = (float*)alloc(4096);
  float* b_kc = (float*)alloc(4096);
  float* b_vc = (float*)alloc(4096);
  float* inv_rs = (float*)alloc(32768);

  // aliases into ctx_b region (dead after the VT GEMM)
  char* ar = (char*)ctx_b;
  u16* qhb    = (u16*)(ar);               // 1,048,576 B
  u16* attn_b = (u16*)(ar + 1048576);     // 1,048,576 B
  u16* xb     = (u16*)(ar + 2097152);     // 1,048,576 B
  u16* h1     = (u16*)(ar + 3145728);     // 4,194,304 B
  float* ao   = (float*)(ar + 7340032);   // 2,097,152 B
  float* xf   = (float*)(ar + 9437184);   // 2,097,152 B
  float* fo   = (float*)(ar + 11534336);  // 2,097,152 B

  // ---- fused casts: ctx, latents, in_wq, in_wk, in_wv, out_w, ff_w1, ff_w2 ----
  fused_cast_kernel<<<dim3(29184), 256, 0, stream>>>(
      context, latents, in_wq, in_wk, in_wv, out_w, ff_w1, ff_w2,
      ctx_b, lat_b, wiq, wik, wiv, wob, wf1b, wf2b);

  // ---- cast+transpose external weights ----
  castT_kernel<<<dim3(32, 32), 256, 0, stream>>>(q_w, qwT);
  castT_kernel<<<dim3(32, 32), 256, 0, stream>>>(k_w, kwT);
  castT_kernel<<<dim3(32, 32), 256, 0, stream>>>(v_w, vwT);

  // ---- composed biases ----
  biascomp_kernel<<<dim3(1024), 256, 0, stream>>>(in_wq, q_b, in_bq, b_qc);
  biascomp_kernel<<<dim3(1024), 256, 0, stream>>>(in_wk, k_b, in_bk, b_kc);
  biascomp_kernel<<<dim3(1024), 256, 0, stream>>>(in_wv, v_b, in_bv, b_vc);

  // ---- composed weights: Wc[o,i] = sum_j in_w[o,j] * wT[i,j] ----
  gemm64<1, 0><<<dim3(16, 16), 256, 0, stream>>>(wiq, qwT, nullptr, wqc,
      1024, 1024, 1024, 1024, 1024, 1024);
  gemm64<1, 0><<<dim3(16, 16), 256, 0, stream>>>(wik, kwT, nullptr, wkc,
      1024, 1024, 1024, 1024, 1024, 1024);
  gemm64<1, 0><<<dim3(16, 16), 256, 0, stream>>>(wiv, vwT, nullptr, wvc,
      1024, 1024, 1024, 1024, 1024, 1024);

  // ---- KH = ctx * Wkc^T + b_kc  [16384,1024] ----
  gemm_bt<1, 1><<<dim3(8, 128, 1), 256, 0, stream>>>(ctx_b, wkc, b_kc, kh,
      16384, 1024, 1024, 1024, 1024, 1024, 0, 0, 0);
  // ---- VT[b][d][s] = Wvc . ctx[b]^T + b_vc  (batched, K-major output) ----
  gemm_bt<1, 2><<<dim3(16, 8, 8), 256, 0, stream>>>(wvc, ctx_b, b_vc, vt,
      1024, 2048, 1024, 1024, 1024, 2048, 0, 2048LL * 1024, 1024LL * 2048);
  // ---- QH = lat * Wqc^T + b_qc  [512,1024] (writes into freed ctx region) ----
  gemm64<1, 1><<<dim3(16, 8), 256, 0, stream>>>(lat_b, wqc, b_qc, qhb,
      512, 1024, 1024, 1024, 1024, 1024);

  // ---- attention ----
  scores_kernel<<<dim3(8, 128), 256, 0, stream>>>(qhb, kh, cmask, probs);
  rowsum_kernel<<<dim3(8192), 256, 0, stream>>>(probs, inv_rs);
  pv_part_kernel<<<dim3(4, 128), 256, 0, stream>>>(probs, vt, pvp);
  pv_reduce_kernel<<<dim3(512), 256, 0, stream>>>(pvp, inv_rs, attn_b);
  mean_kernel<<<dim3(512), 256, 0, stream>>>(probs, inv_rs, (float*)d_out + 524288);

  // ---- out projection + LN1 ----
  gemm64<0, 1><<<dim3(16, 8), 256, 0, stream>>>(attn_b, wob, out_b, ao,
      512, 1024, 1024, 1024, 1024, 1024);
  ln_kernel<<<dim3(512), 256, 0, stream>>>(latents, ao, ln1_g, ln1_b, xf, xb);

  // ---- FF ----
  gemm64<2, 1><<<dim3(64, 8), 256, 0, stream>>>(xb, wf1b, ff_b1, h1,
      512, 4096, 1024, 1024, 1024, 4096);
  gemm64<0, 1><<<dim3(16, 8), 256, 0, stream>>>(h1, wf2b, ff_b2, fo,
      512, 1024, 4096, 4096, 4096, 1024);
  ln_kernel<<<dim3(512), 256, 0, stream>>>(xf, fo, ln2_g, ln2_b, (float*)d_out, nullptr);
}

// Round 3
// 450.727 us; speedup vs baseline: 1.5607x; 1.1376x over previous
//
#include <hip/hip_runtime.h>
#include <hip/hip_bf16.h>

typedef unsigned short u16;
typedef unsigned int u32;
typedef __attribute__((ext_vector_type(8))) short bf16x8;
typedef __attribute__((ext_vector_type(4))) float f32x4;

typedef __attribute__((address_space(1))) const u32 as1_u32;
typedef __attribute__((address_space(3))) u32 as3_u32;

#define MFMA16(a, b, c) __builtin_amdgcn_mfma_f32_16x16x32_bf16(a, b, c, 0, 0, 0)

__device__ __forceinline__ void gld16(const void* g, void* l) {
  __builtin_amdgcn_global_load_lds((as1_u32*)g, (as3_u32*)l, 16, 0, 0);
}

__device__ __forceinline__ float b2f(u16 u) { return __uint_as_float(((u32)u) << 16); }
__device__ __forceinline__ u16 f2b(float f) {
  u32 x = __float_as_uint(f);
  u32 r = (x + 0x7fffu + ((x >> 16) & 1u)) >> 16;
  return (u16)r;
}

__device__ __forceinline__ float wave_red(float v) {
  for (int o = 32; o; o >>= 1) v += __shfl_down(v, o);
  return v;
}

// ---------------- fused segmented cast f32 -> bf16 ----------------
__global__ __launch_bounds__(256) void fused_cast_kernel(
    const float* __restrict__ s0, const float* __restrict__ s1,
    const float* __restrict__ s2, const float* __restrict__ s3,
    const float* __restrict__ s4, const float* __restrict__ s5,
    const float* __restrict__ s6, const float* __restrict__ s7,
    u16* __restrict__ d0, u16* __restrict__ d1, u16* __restrict__ d2,
    u16* __restrict__ d3, u16* __restrict__ d4, u16* __restrict__ d5,
    u16* __restrict__ d6, u16* __restrict__ d7) {
  const unsigned base = blockIdx.x * 1024u;
  const float* src;
  u16* dst;
  unsigned off;
  if (base < 16777216u)      { src = s0; dst = d0; off = 0u; }
  else if (base < 17301504u) { src = s1; dst = d1; off = 16777216u; }
  else if (base < 18350080u) { src = s2; dst = d2; off = 17301504u; }
  else if (base < 19398656u) { src = s3; dst = d3; off = 18350080u; }
  else if (base < 20447232u) { src = s4; dst = d4; off = 19398656u; }
  else if (base < 21495808u) { src = s5; dst = d5; off = 20447232u; }
  else if (base < 25690112u) { src = s6; dst = d6; off = 21495808u; }
  else                       { src = s7; dst = d7; off = 25690112u; }
  const unsigned i = base - off + threadIdx.x * 4u;
  float4 v = *reinterpret_cast<const float4*>(src + i);
  ushort4 o;
  o.x = f2b(v.x); o.y = f2b(v.y); o.z = f2b(v.z); o.w = f2b(v.w);
  *reinterpret_cast<ushort4*>(dst + i) = o;
}

// ---------------- cast + transpose: out[i][j] = bf16(in[j][i]), 1024x1024 ----------------
__global__ __launch_bounds__(256) void castT_kernel(const float* __restrict__ in,
                                                    u16* __restrict__ out) {
  __shared__ u16 sm[32][33];
  const int r0 = blockIdx.y * 32, c0 = blockIdx.x * 32;
  const int t = threadIdx.x;
  const int r = t >> 3, c4 = (t & 7) * 4;
  float4 v = *reinterpret_cast<const float4*>(in + (size_t)(r0 + r) * 1024 + c0 + c4);
  sm[c4 + 0][r] = f2b(v.x);
  sm[c4 + 1][r] = f2b(v.y);
  sm[c4 + 2][r] = f2b(v.z);
  sm[c4 + 3][r] = f2b(v.w);
  __syncthreads();
  ushort4 o;
  o.x = sm[r][c4 + 0]; o.y = sm[r][c4 + 1]; o.z = sm[r][c4 + 2]; o.w = sm[r][c4 + 3];
  *reinterpret_cast<ushort4*>(out + (size_t)(c0 + r) * 1024 + r0 + c4) = o;
}

// ---------------- bias compose: out[o] = dot(A[o,:1024], b) + b2[o] ----------------
__global__ __launch_bounds__(256) void biascomp_kernel(const float* __restrict__ A,
                                                       const float* __restrict__ b,
                                                       const float* __restrict__ b2,
                                                       float* __restrict__ out) {
  __shared__ float red[4];
  const int row = blockIdx.x;
  const int t = threadIdx.x;
  float4 va = *reinterpret_cast<const float4*>(A + (size_t)row * 1024 + t * 4);
  float4 vb = *reinterpret_cast<const float4*>(b + t * 4);
  float s = va.x * vb.x + va.y * vb.y + va.z * vb.z + va.w * vb.w;
  s = wave_red(s);
  if ((t & 63) == 0) red[t >> 6] = s;
  __syncthreads();
  if (t == 0) out[row] = red[0] + red[1] + red[2] + red[3] + b2[row];
}

// ---------------- 128x128 GEMM: C[m,n] = sum_k A[m,k]*W[n,k] (+bias) ----------------
// EPI: 0 = f32, 1 = bf16, 2 = gelu->bf16 ; BIASM: 0 none, 1 bias[col], 2 bias[row]
// SWZ: XCD-aware block swizzle (requires total blocks % 8 == 0)
template <int EPI, int BIASM, int SWZ>
__global__ __launch_bounds__(256) void gemm_bt(
    const u16* __restrict__ A, const u16* __restrict__ W, const float* __restrict__ bias,
    void* __restrict__ Cout, int M, int N, int K, int lda, int ldw, int ldc,
    long long bsA, long long bsW, long long bsC) {
  __shared__ u16 a_sm[128 * 32];
  __shared__ u16 b_sm[128 * 32];
  int bx = blockIdx.x, by = blockIdx.y, bz = blockIdx.z;
  if (SWZ) {
    const int gx = gridDim.x, gy = gridDim.y;
    const int lin = bx + gx * (by + gy * bz);
    const int nwg = gx * gy * gridDim.z;
    const int swz = (lin & 7) * (nwg >> 3) + (lin >> 3);
    bx = swz % gx;
    const int t2 = swz / gx;
    by = t2 % gy;
    bz = t2 / gy;
  }
  const int t = threadIdx.x;
  const int lane = t & 63;
  const int wv = t >> 6;
  const int wm = wv >> 1, wn = wv & 1;
  const int l15 = lane & 15, l4 = lane >> 4;
  const long long zb = bz;

  const u16* Ab = A + zb * bsA;
  const u16* Wb = W + zb * bsW;

  const u16* ag = Ab + (size_t)(by * 128 + (t >> 2)) * lda + (t & 3) * 8;
  const u16* wg = Wb + (size_t)(bx * 128 + (t >> 2)) * ldw + (t & 3) * 8;
  u16* ad = a_sm + t * 8;
  u16* bd = b_sm + t * 8;

  f32x4 acc[4][4] = {};

  for (int k0 = 0; k0 < K; k0 += 32) {
    gld16(ag, ad);
    gld16(ag + (size_t)64 * lda, ad + 64 * 32);
    gld16(wg, bd);
    gld16(wg + (size_t)64 * ldw, bd + 64 * 32);
    ag += 32; wg += 32;
    __syncthreads();
    bf16x8 af[4], bf[4];
#pragma unroll
    for (int m = 0; m < 4; m++)
      af[m] = *reinterpret_cast<const bf16x8*>(&a_sm[(wm * 64 + m * 16 + l15) * 32 + l4 * 8]);
#pragma unroll
    for (int n = 0; n < 4; n++)
      bf[n] = *reinterpret_cast<const bf16x8*>(&b_sm[(wn * 64 + n * 16 + l15) * 32 + l4 * 8]);
#pragma unroll
    for (int m = 0; m < 4; m++)
#pragma unroll
      for (int n = 0; n < 4; n++)
        acc[m][n] = MFMA16(af[m], bf[n], acc[m][n]);
    __syncthreads();
  }

  const int gm0 = by * 128 + wm * 64;
  const int gn0 = bx * 128 + wn * 64;
  float* cf = reinterpret_cast<float*>(Cout) + zb * bsC;
  u16* cb = reinterpret_cast<u16*>(Cout) + zb * bsC;
#pragma unroll
  for (int m = 0; m < 4; m++) {
#pragma unroll
    for (int n = 0; n < 4; n++) {
      const int col = gn0 + n * 16 + l15;
      float bc = (BIASM == 1) ? bias[col] : 0.f;
#pragma unroll
      for (int r = 0; r < 4; r++) {
        const int row = gm0 + m * 16 + l4 * 4 + r;
        float v = acc[m][n][r];
        if (BIASM == 1) v += bc;
        if (BIASM == 2) v += bias[row];
        if (EPI == 2) v = 0.5f * v * (1.0f + erff(v * 0.70710678118654752f));
        if (EPI == 0) cf[(size_t)row * ldc + col] = v;
        else          cb[(size_t)row * ldc + col] = f2b(v);
      }
    }
  }
}

// ---------------- 64x64 GEMM (small-shape variant) ----------------
template <int EPI, int BIASM>
__global__ __launch_bounds__(256) void gemm64(
    const u16* __restrict__ A, const u16* __restrict__ W, const float* __restrict__ bias,
    void* __restrict__ Cout, int M, int N, int K, int lda, int ldw, int ldc) {
  __shared__ u16 a_sm[64 * 32];
  __shared__ u16 b_sm[64 * 32];
  const int t = threadIdx.x;
  const int lane = t & 63;
  const int wv = t >> 6;
  const int wm = wv >> 1, wn = wv & 1;
  const int l15 = lane & 15, l4 = lane >> 4;

  const u16* ag = A + (size_t)(blockIdx.y * 64 + (t >> 2)) * lda + (t & 3) * 8;
  const u16* wg = W + (size_t)(blockIdx.x * 64 + (t >> 2)) * ldw + (t & 3) * 8;
  u16* ad = a_sm + t * 8;
  u16* bd = b_sm + t * 8;

  f32x4 acc[2][2] = {};

  for (int k0 = 0; k0 < K; k0 += 32) {
    gld16(ag, ad);
    gld16(wg, bd);
    ag += 32; wg += 32;
    __syncthreads();
    bf16x8 af[2], bf[2];
#pragma unroll
    for (int m = 0; m < 2; m++)
      af[m] = *reinterpret_cast<const bf16x8*>(&a_sm[(wm * 32 + m * 16 + l15) * 32 + l4 * 8]);
#pragma unroll
    for (int n = 0; n < 2; n++)
      bf[n] = *reinterpret_cast<const bf16x8*>(&b_sm[(wn * 32 + n * 16 + l15) * 32 + l4 * 8]);
#pragma unroll
    for (int m = 0; m < 2; m++)
#pragma unroll
      for (int n = 0; n < 2; n++)
        acc[m][n] = MFMA16(af[m], bf[n], acc[m][n]);
    __syncthreads();
  }

  const int gm0 = blockIdx.y * 64 + wm * 32;
  const int gn0 = blockIdx.x * 64 + wn * 32;
  float* cf = reinterpret_cast<float*>(Cout);
  u16* cb = reinterpret_cast<u16*>(Cout);
#pragma unroll
  for (int m = 0; m < 2; m++) {
#pragma unroll
    for (int n = 0; n < 2; n++) {
      const int col = gn0 + n * 16 + l15;
      float bc = (BIASM == 1) ? bias[col] : 0.f;
#pragma unroll
      for (int r = 0; r < 4; r++) {
        const int row = gm0 + m * 16 + l4 * 4 + r;
        float v = acc[m][n][r];
        if (BIASM == 1) v += bc;
        if (BIASM == 2) v += bias[row];
        if (EPI == 2) v = 0.5f * v * (1.0f + erff(v * 0.70710678118654752f));
        if (EPI == 0) cf[(size_t)row * ldc + col] = v;
        else          cb[(size_t)row * ldc + col] = f2b(v);
      }
    }
  }
}

// ---------------- 64x64 split-K GEMM -> f32 partials ----------------
// grid (N/64, M/64, S); part[z][row][col], k-chunk = Kc
__global__ __launch_bounds__(256) void gemm64sk(
    const u16* __restrict__ A, const u16* __restrict__ W, float* __restrict__ part,
    int N, int Kc, int lda, int ldw) {
  __shared__ u16 a_sm[64 * 32];
  __shared__ u16 b_sm[64 * 32];
  const int t = threadIdx.x;
  const int lane = t & 63;
  const int wv = t >> 6;
  const int wm = wv >> 1, wn = wv & 1;
  const int l15 = lane & 15, l4 = lane >> 4;
  const int z = blockIdx.z;

  const u16* ag = A + (size_t)(blockIdx.y * 64 + (t >> 2)) * lda + z * Kc + (t & 3) * 8;
  const u16* wg = W + (size_t)(blockIdx.x * 64 + (t >> 2)) * ldw + z * Kc + (t & 3) * 8;
  u16* ad = a_sm + t * 8;
  u16* bd = b_sm + t * 8;

  f32x4 acc[2][2] = {};

  for (int k0 = 0; k0 < Kc; k0 += 32) {
    gld16(ag, ad);
    gld16(wg, bd);
    ag += 32; wg += 32;
    __syncthreads();
    bf16x8 af[2], bf[2];
#pragma unroll
    for (int m = 0; m < 2; m++)
      af[m] = *reinterpret_cast<const bf16x8*>(&a_sm[(wm * 32 + m * 16 + l15) * 32 + l4 * 8]);
#pragma unroll
    for (int n = 0; n < 2; n++)
      bf[n] = *reinterpret_cast<const bf16x8*>(&b_sm[(wn * 32 + n * 16 + l15) * 32 + l4 * 8]);
#pragma unroll
    for (int m = 0; m < 2; m++)
#pragma unroll
      for (int n = 0; n < 2; n++)
        acc[m][n] = MFMA16(af[m], bf[n], acc[m][n]);
    __syncthreads();
  }

  const int Mtot = gridDim.y * 64;
  float* po = part + (size_t)z * Mtot * N;
  const int gm0 = blockIdx.y * 64 + wm * 32;
  const int gn0 = blockIdx.x * 64 + wn * 32;
#pragma unroll
  for (int m = 0; m < 2; m++) {
#pragma unroll
    for (int n = 0; n < 2; n++) {
      const int col = gn0 + n * 16 + l15;
#pragma unroll
      for (int r = 0; r < 4; r++) {
        const int row = gm0 + m * 16 + l4 * 4 + r;
        po[(size_t)row * N + col] = acc[m][n][r];
      }
    }
  }
}

// ---------------- reduce 2 partials + bias -> bf16 (512x1024) ----------------
__global__ __launch_bounds__(256) void redb_kernel(const float* __restrict__ p,
                                                   const float* __restrict__ bias,
                                                   u16* __restrict__ out) {
  const int i = (blockIdx.x * 256 + threadIdx.x) * 4;
  const int col = i & 1023;
  float4 v0 = *reinterpret_cast<const float4*>(p + i);
  float4 v1 = *reinterpret_cast<const float4*>(p + 524288 + i);
  float4 vb = *reinterpret_cast<const float4*>(bias + col);
  ushort4 o;
  o.x = f2b(v0.x + v1.x + vb.x);
  o.y = f2b(v0.y + v1.y + vb.y);
  o.z = f2b(v0.z + v1.z + vb.z);
  o.w = f2b(v0.w + v1.w + vb.w);
  *reinterpret_cast<ushort4*>(out + i) = o;
}

// ---------------- scores: probs = exp(QK^T/8) (masked->0), bf16, LDS-swizzled ----------------
__global__ __launch_bounds__(256) void scores_kernel(const u16* __restrict__ QH,
                                                     const u16* __restrict__ KH,
                                                     const int* __restrict__ mask,
                                                     u16* __restrict__ probs) {
  __shared__ u16 q_sm[64 * 64];
  __shared__ u16 k_sm[256 * 64];
  int bx = blockIdx.x, by = blockIdx.y;
  {
    const int lin = bx + 8 * by;
    const int swz = (lin & 7) * 128 + (lin >> 3);
    bx = swz & 7;
    by = swz >> 3;
  }
  const int bh = by;
  const int b = bh >> 4, h = bh & 15;
  const int sc = bx;
  const int t = threadIdx.x;
  const int lane = t & 63;
  const int wv = t >> 6;
  const int l15 = lane & 15, l4 = lane >> 4;
  const int x7 = l15 & 7;

  const int r = t >> 3;
  const int cs = (t & 7) ^ (r & 7);  // pre-swizzled source chunk
  {
    const u16* src = QH + (size_t)(b * 64 + r) * 1024 + h * 64 + cs * 8;
    u16* dst = q_sm + t * 8;
    gld16(src, dst);
    gld16(src + (size_t)32 * 1024, dst + 32 * 64);
  }
  {
    const u16* src = KH + (size_t)(b * 2048 + sc * 256 + r) * 1024 + h * 64 + cs * 8;
    u16* dst = k_sm + t * 8;
#pragma unroll
    for (int i = 0; i < 8; i++)
      gld16(src + (size_t)i * 32 * 1024, dst + i * 32 * 64);
  }
  __syncthreads();

  f32x4 acc[4][4] = {};
#pragma unroll
  for (int ks = 0; ks < 2; ks++) {
    bf16x8 af[4], bf[4];
#pragma unroll
    for (int m = 0; m < 4; m++)
      af[m] = *reinterpret_cast<const bf16x8*>(
          &q_sm[(m * 16 + l15) * 64 + ((ks * 4 + l4) ^ x7) * 8]);
#pragma unroll
    for (int n = 0; n < 4; n++)
      bf[n] = *reinterpret_cast<const bf16x8*>(
          &k_sm[(wv * 64 + n * 16 + l15) * 64 + ((ks * 4 + l4) ^ x7) * 8]);
#pragma unroll
    for (int m = 0; m < 4; m++)
#pragma unroll
      for (int n = 0; n < 4; n++)
        acc[m][n] = MFMA16(af[m], bf[n], acc[m][n]);
  }

#pragma unroll
  for (int n = 0; n < 4; n++) {
    const int sg = sc * 256 + wv * 64 + n * 16 + l15;
    const bool keep = mask[b * 2048 + sg] != 0;
#pragma unroll
    for (int m = 0; m < 4; m++) {
#pragma unroll
      for (int r2 = 0; r2 < 4; r2++) {
        const int row = m * 16 + l4 * 4 + r2;
        float p = keep ? __expf(acc[m][n][r2] * 0.125f) : 0.f;
        probs[((size_t)bh * 64 + row) * 2048 + sg] = f2b(p);
      }
    }
  }
}

// ---------------- rowsum -> 1/sum ----------------
__global__ __launch_bounds__(256) void rowsum_kernel(const u16* __restrict__ probs,
                                                     float* __restrict__ inv) {
  __shared__ float red[4];
  const int row = blockIdx.x;
  const int t = threadIdx.x;
  uint4 r4 = *reinterpret_cast<const uint4*>(probs + (size_t)row * 2048 + t * 8);
  float s = b2f((u16)(r4.x & 0xffffu)) + b2f((u16)(r4.x >> 16)) +
            b2f((u16)(r4.y & 0xffffu)) + b2f((u16)(r4.y >> 16)) +
            b2f((u16)(r4.z & 0xffffu)) + b2f((u16)(r4.z >> 16)) +
            b2f((u16)(r4.w & 0xffffu)) + b2f((u16)(r4.w >> 16));
  s = wave_red(s);
  if ((t & 63) == 0) red[t >> 6] = s;
  __syncthreads();
  if (t == 0) inv[row] = 1.0f / (red[0] + red[1] + red[2] + red[3]);
}

// ---------------- PV split-K partials (LDS-swizzled) ----------------
__global__ __launch_bounds__(256) void pv_part_kernel(const u16* __restrict__ probs,
                                                      const u16* __restrict__ VT,
                                                      float* __restrict__ part) {
  __shared__ u16 a_sm[64 * 64];
  __shared__ u16 b_sm[64 * 64];
  int bx = blockIdx.x, by = blockIdx.y;
  {
    const int lin = bx + 4 * by;
    const int swz = (lin & 7) * 64 + (lin >> 3);
    bx = swz & 3;
    by = swz >> 2;
  }
  const int c = bx;
  const int bh = by;
  const int b = bh >> 4, h = bh & 15;
  const u16* Ab = probs + (size_t)bh * 64 * 2048;
  const u16* Bb = VT + ((size_t)b * 1024 + h * 64) * 2048;
  const int t = threadIdx.x;
  const int lane = t & 63;
  const int wv = t >> 6;
  const int wm = wv >> 1, wn = wv & 1;
  const int l15 = lane & 15, l4 = lane >> 4;
  const int x7 = l15 & 7;

  const int r = t >> 3;
  const int cs = (t & 7) ^ (r & 7);

  f32x4 acc[2][2] = {};
  for (int k0 = c * 512; k0 < c * 512 + 512; k0 += 64) {
    const u16* as = Ab + (size_t)r * 2048 + k0 + cs * 8;
    const u16* bs = Bb + (size_t)r * 2048 + k0 + cs * 8;
    u16* ad = a_sm + t * 8;
    u16* bd = b_sm + t * 8;
    gld16(as, ad);
    gld16(as + (size_t)32 * 2048, ad + 32 * 64);
    gld16(bs, bd);
    gld16(bs + (size_t)32 * 2048, bd + 32 * 64);
    __syncthreads();
#pragma unroll
    for (int ks = 0; ks < 2; ks++) {
      bf16x8 af[2], bf[2];
#pragma unroll
      for (int m = 0; m < 2; m++)
        af[m] = *reinterpret_cast<const bf16x8*>(
            &a_sm[(wm * 32 + m * 16 + l15) * 64 + ((ks * 4 + l4) ^ x7) * 8]);
#pragma unroll
      for (int n = 0; n < 2; n++)
        bf[n] = *reinterpret_cast<const bf16x8*>(
            &b_sm[(wn * 32 + n * 16 + l15) * 64 + ((ks * 4 + l4) ^ x7) * 8]);
#pragma unroll
      for (int m = 0; m < 2; m++)
#pragma unroll
        for (int n = 0; n < 2; n++)
          acc[m][n] = MFMA16(af[m], bf[n], acc[m][n]);
    }
    __syncthreads();
  }

  float* po = part + ((size_t)(bh * 4 + c)) * 4096;
#pragma unroll
  for (int m = 0; m < 2; m++) {
#pragma unroll
    for (int n = 0; n < 2; n++) {
#pragma unroll
      for (int r2 = 0; r2 < 4; r2++) {
        const int l = wm * 32 + m * 16 + l4 * 4 + r2;
        const int hd = wn * 32 + n * 16 + l15;
        po[l * 64 + hd] = acc[m][n][r2];
      }
    }
  }
}

// ---------------- PV reduce: attn = (sum_c part) * inv ----------------
__global__ __launch_bounds__(256) void pv_reduce_kernel(const float* __restrict__ part,
                                                        const float* __restrict__ inv,
                                                        u16* __restrict__ attn) {
  const int t = threadIdx.x;
  const int e0 = (blockIdx.x * 256 + t) * 4;
  const int bh = e0 >> 12;
  const int r = e0 & 4095;
  const int l = r >> 6, hd = r & 63;
  const int b = bh >> 4, h = bh & 15;
  const float* p = part + ((size_t)bh * 4) * 4096 + r;
  float4 v0 = *reinterpret_cast<const float4*>(p);
  float4 v1 = *reinterpret_cast<const float4*>(p + 4096);
  float4 v2 = *reinterpret_cast<const float4*>(p + 8192);
  float4 v3 = *reinterpret_cast<const float4*>(p + 12288);
  const float sc = inv[bh * 64 + l];
  ushort4 o;
  o.x = f2b((v0.x + v1.x + v2.x + v3.x) * sc);
  o.y = f2b((v0.y + v1.y + v2.y + v3.y) * sc);
  o.z = f2b((v0.z + v1.z + v2.z + v3.z) * sc);
  o.w = f2b((v0.w + v1.w + v2.w + v3.w) * sc);
  *reinterpret_cast<ushort4*>(attn + (size_t)(b * 64 + l) * 1024 + h * 64 + hd) = o;
}

// ---------------- head-mean of normalized probs -> attn_weights [B,L,S] f32 ----------------
__global__ __launch_bounds__(256) void mean_kernel(const u16* __restrict__ probs,
                                                   const float* __restrict__ inv,
                                                   float* __restrict__ outw) {
  __shared__ float s_inv[16];
  const int bl = blockIdx.x;
  const int b = bl >> 6, l = bl & 63;
  const int t = threadIdx.x;
  if (t < 16) s_inv[t] = inv[(b * 16 + t) * 64 + l] * 0.0625f;
  __syncthreads();
  float av[8] = {0.f, 0.f, 0.f, 0.f, 0.f, 0.f, 0.f, 0.f};
  for (int h = 0; h < 16; h++) {
    uint4 r4 = *reinterpret_cast<const uint4*>(
        probs + ((size_t)((b * 16 + h) * 64 + l)) * 2048 + t * 8);
    float sc = s_inv[h];
    av[0] += b2f((u16)(r4.x & 0xffffu)) * sc; av[1] += b2f((u16)(r4.x >> 16)) * sc;
    av[2] += b2f((u16)(r4.y & 0xffffu)) * sc; av[3] += b2f((u16)(r4.y >> 16)) * sc;
    av[4] += b2f((u16)(r4.z & 0xffffu)) * sc; av[5] += b2f((u16)(r4.z >> 16)) * sc;
    av[6] += b2f((u16)(r4.w & 0xffffu)) * sc; av[7] += b2f((u16)(r4.w >> 16)) * sc;
  }
  float* o = outw + (size_t)bl * 2048 + t * 8;
  *reinterpret_cast<float4*>(o) = make_float4(av[0], av[1], av[2], av[3]);
  *reinterpret_cast<float4*>(o + 4) = make_float4(av[4], av[5], av[6], av[7]);
}

// ---------------- LayerNorm with NP f32 partial addends + bias ----------------
// x = a + sum_p parts[p] + bias[col]; out = LN(x)*g+beta
template <int NP>
__global__ __launch_bounds__(256) void lnp_kernel(const float* __restrict__ a,
                                                  const float* __restrict__ parts,
                                                  const float* __restrict__ bias,
                                                  const float* __restrict__ g,
                                                  const float* __restrict__ bet,
                                                  float* __restrict__ outf,
                                                  u16* __restrict__ outb) {
  __shared__ float red[8];
  __shared__ float mv[2];
  const int row = blockIdx.x;
  const int t = threadIdx.x;
  const size_t idx = (size_t)row * 1024 + t * 4;
  const float4 va = *reinterpret_cast<const float4*>(a + idx);
  const float4 vb = *reinterpret_cast<const float4*>(bias + t * 4);
  float x0 = va.x + vb.x, x1 = va.y + vb.y, x2 = va.z + vb.z, x3 = va.w + vb.w;
#pragma unroll
  for (int p = 0; p < NP; p++) {
    const float4 vp = *reinterpret_cast<const float4*>(parts + (size_t)p * 524288 + idx);
    x0 += vp.x; x1 += vp.y; x2 += vp.z; x3 += vp.w;
  }
  float s = x0 + x1 + x2 + x3;
  float q = x0 * x0 + x1 * x1 + x2 * x2 + x3 * x3;
  s = wave_red(s);
  q = wave_red(q);
  if ((t & 63) == 0) { red[t >> 6] = s; red[4 + (t >> 6)] = q; }
  __syncthreads();
  if (t == 0) {
    float S = red[0] + red[1] + red[2] + red[3];
    float Q = red[4] + red[5] + red[6] + red[7];
    float mu = S * (1.f / 1024.f);
    float var = Q * (1.f / 1024.f) - mu * mu;
    mv[0] = mu;
    mv[1] = rsqrtf(var + 1e-5f);
  }
  __syncthreads();
  const float mu = mv[0], rs = mv[1];
  const float4 vg = *reinterpret_cast<const float4*>(g + t * 4);
  const float4 ve = *reinterpret_cast<const float4*>(bet + t * 4);
  float y0 = (x0 - mu) * rs * vg.x + ve.x;
  float y1 = (x1 - mu) * rs * vg.y + ve.y;
  float y2 = (x2 - mu) * rs * vg.z + ve.z;
  float y3 = (x3 - mu) * rs * vg.w + ve.w;
  *reinterpret_cast<float4*>(outf + idx) = make_float4(y0, y1, y2, y3);
  if (outb) {
    ushort4 o;
    o.x = f2b(y0); o.y = f2b(y1); o.z = f2b(y2); o.w = f2b(y3);
    *reinterpret_cast<ushort4*>(outb + idx) = o;
  }
}

extern "C" void kernel_launch(void* const* d_in, const int* in_sizes, int n_in,
                              void* d_out, int out_size, void* d_ws, size_t ws_size,
                              hipStream_t stream) {
  const float* latents = (const float*)d_in[0];
  const float* context = (const float*)d_in[1];
  const int* cmask = (const int*)d_in[2];
  const float* q_w = (const float*)d_in[3];   const float* q_b = (const float*)d_in[4];
  const float* k_w = (const float*)d_in[5];   const float* k_b = (const float*)d_in[6];
  const float* v_w = (const float*)d_in[7];   const float* v_b = (const float*)d_in[8];
  const float* in_wq = (const float*)d_in[9]; const float* in_bq = (const float*)d_in[10];
  const float* in_wk = (const float*)d_in[11]; const float* in_bk = (const float*)d_in[12];
  const float* in_wv = (const float*)d_in[13]; const float* in_bv = (const float*)d_in[14];
  const float* out_w = (const float*)d_in[15]; const float* out_b = (const float*)d_in[16];
  const float* ln1_g = (const float*)d_in[17]; const float* ln1_b = (const float*)d_in[18];
  const float* ln2_g = (const float*)d_in[19]; const float* ln2_b = (const float*)d_in[20];
  const float* ff_w1 = (const float*)d_in[21]; const float* ff_b1 = (const float*)d_in[22];
  const float* ff_w2 = (const float*)d_in[23]; const float* ff_b2 = (const float*)d_in[24];

  char* wsb = (char*)d_ws;
  size_t off = 0;
  auto alloc = [&](size_t bytes) -> char* {
    char* p = wsb + off;
    off = (off + bytes + 255) & ~(size_t)255;
    return p;
  };

  u16* ctx_b = (u16*)alloc(33554432);   // [16384,1024] bf16; region reused later
  u16* kh    = (u16*)alloc(33554432);   // [16384,1024] bf16 (KH)
  u16* vt    = (u16*)alloc(33554432);   // [8][1024][2048] bf16 (V^T per batch)
  u16* probs = (u16*)alloc(33554432);   // [128][64][2048] bf16
  float* pvp = (float*)alloc(8388608);  // [128][4][4096] f32 PV partials
  u16* lat_b = (u16*)alloc(1048576);
  u16* wiq   = (u16*)alloc(2097152);
  u16* wik   = (u16*)alloc(2097152);
  u16* wiv   = (u16*)alloc(2097152);
  u16* qwT   = (u16*)alloc(2097152);
  u16* kwT   = (u16*)alloc(2097152);
  u16* vwT   = (u16*)alloc(2097152);
  u16* wqc   = (u16*)alloc(2097152);
  u16* wkc   = (u16*)alloc(2097152);
  u16* wvc   = (u16*)alloc(2097152);
  u16* wob   = (u16*)alloc(2097152);
  u16* wf1b  = (u16*)alloc(8388608);
  u16* wf2b  = (u16*)alloc(8388608);
  float* b_qc = (float*)alloc(4096);
  float* b_kc = (float*)alloc(4096);
  float* b_vc = (float*)alloc(4096);
  float* inv_rs = (float*)alloc(32768);
  float* partsQ = (float*)alloc(4194304);   // 2 x [512,1024] f32
  float* partsO = (float*)alloc(4194304);   // 2 x [512,1024] f32
  float* partsF = (float*)alloc(16777216);  // 4 x [512,1024] f32

  // aliases into ctx_b region (dead after the VT GEMM)
  char* ar = (char*)ctx_b;
  u16* qhb    = (u16*)(ar);               // 1 MB
  u16* attn_b = (u16*)(ar + 1048576);     // 1 MB
  u16* xb     = (u16*)(ar + 2097152);     // 1 MB
  u16* h1     = (u16*)(ar + 3145728);     // 4 MB
  float* xf   = (float*)(ar + 7340032);   // 2 MB

  // ---- fused casts: ctx, latents, in_wq, in_wk, in_wv, out_w, ff_w1, ff_w2 ----
  fused_cast_kernel<<<dim3(29184), 256, 0, stream>>>(
      context, latents, in_wq, in_wk, in_wv, out_w, ff_w1, ff_w2,
      ctx_b, lat_b, wiq, wik, wiv, wob, wf1b, wf2b);

  // ---- cast+transpose external weights ----
  castT_kernel<<<dim3(32, 32), 256, 0, stream>>>(q_w, qwT);
  castT_kernel<<<dim3(32, 32), 256, 0, stream>>>(k_w, kwT);
  castT_kernel<<<dim3(32, 32), 256, 0, stream>>>(v_w, vwT);

  // ---- composed biases ----
  biascomp_kernel<<<dim3(1024), 256, 0, stream>>>(in_wq, q_b, in_bq, b_qc);
  biascomp_kernel<<<dim3(1024), 256, 0, stream>>>(in_wk, k_b, in_bk, b_kc);
  biascomp_kernel<<<dim3(1024), 256, 0, stream>>>(in_wv, v_b, in_bv, b_vc);

  // ---- composed weights, batched z=3 (wiq/wik/wiv, qwT/kwT/vwT, wqc/wkc/wvc contiguous) ----
  gemm_bt<1, 0, 1><<<dim3(8, 8, 3), 256, 0, stream>>>(wiq, qwT, nullptr, wqc,
      1024, 1024, 1024, 1024, 1024, 1024, 1048576, 1048576, 1048576);

  // ---- KH = ctx * Wkc^T + b_kc  [16384,1024] ----
  gemm_bt<1, 1, 1><<<dim3(8, 128, 1), 256, 0, stream>>>(ctx_b, wkc, b_kc, kh,
      16384, 1024, 1024, 1024, 1024, 1024, 0, 0, 0);
  // ---- VT[b][d][s] = Wvc . ctx[b]^T + b_vc  (batched, K-major output) ----
  gemm_bt<1, 2, 1><<<dim3(16, 8, 8), 256, 0, stream>>>(wvc, ctx_b, b_vc, vt,
      1024, 2048, 1024, 1024, 1024, 2048, 0, 2048LL * 1024, 1024LL * 2048);

  // ---- QH = lat * Wqc^T + b_qc (split-K2, writes into freed ctx region) ----
  gemm64sk<<<dim3(16, 8, 2), 256, 0, stream>>>(lat_b, wqc, partsQ, 1024, 512, 1024, 1024);
  redb_kernel<<<dim3(512), 256, 0, stream>>>(partsQ, b_qc, qhb);

  // ---- attention ----
  scores_kernel<<<dim3(8, 128), 256, 0, stream>>>(qhb, kh, cmask, probs);
  rowsum_kernel<<<dim3(8192), 256, 0, stream>>>(probs, inv_rs);
  pv_part_kernel<<<dim3(4, 128), 256, 0, stream>>>(probs, vt, pvp);
  pv_reduce_kernel<<<dim3(512), 256, 0, stream>>>(pvp, inv_rs, attn_b);
  mean_kernel<<<dim3(512), 256, 0, stream>>>(probs, inv_rs, (float*)d_out + 524288);

  // ---- out projection (split-K2) + LN1 (fused reduce + bias) ----
  gemm64sk<<<dim3(16, 8, 2), 256, 0, stream>>>(attn_b, wob, partsO, 1024, 512, 1024, 1024);
  lnp_kernel<2><<<dim3(512), 256, 0, stream>>>(latents, partsO, out_b, ln1_g, ln1_b, xf, xb);

  // ---- FF ----
  gemm64<2, 1><<<dim3(64, 8), 256, 0, stream>>>(xb, wf1b, ff_b1, h1,
      512, 4096, 1024, 1024, 1024, 4096);
  gemm64sk<<<dim3(16, 8, 4), 256, 0, stream>>>(h1, wf2b, partsF, 1024, 1024, 4096, 4096);
  lnp_kernel<4><<<dim3(512), 256, 0, stream>>>(xf, partsF, ff_b2, ln2_g, ln2_b,
                                               (float*)d_out, nullptr);
}

// Round 4
// 401.238 us; speedup vs baseline: 1.7532x; 1.1233x over previous
//
#include <hip/hip_runtime.h>
#include <hip/hip_bf16.h>

typedef unsigned short u16;
typedef unsigned int u32;
typedef __attribute__((ext_vector_type(8))) short bf16x8;
typedef __attribute__((ext_vector_type(4))) float f32x4;

typedef __attribute__((address_space(1))) const u32 as1_u32;
typedef __attribute__((address_space(3))) u32 as3_u32;

#define MFMA16(a, b, c) __builtin_amdgcn_mfma_f32_16x16x32_bf16(a, b, c, 0, 0, 0)

__device__ __forceinline__ void gld16(const void* g, void* l) {
  __builtin_amdgcn_global_load_lds((as1_u32*)g, (as3_u32*)l, 16, 0, 0);
}

__device__ __forceinline__ float b2f(u16 u) { return __uint_as_float(((u32)u) << 16); }
__device__ __forceinline__ u16 f2b(float f) {
  u32 x = __float_as_uint(f);
  u32 r = (x + 0x7fffu + ((x >> 16) & 1u)) >> 16;
  return (u16)r;
}

__device__ __forceinline__ float wave_red(float v) {
  for (int o = 32; o; o >>= 1) v += __shfl_down(v, o);
  return v;
}

// ---------------- fused segmented cast f32 -> bf16 (+ zero the rowsum buffer) ----------------
__global__ __launch_bounds__(256) void fused_cast_kernel(
    const float* __restrict__ s0, const float* __restrict__ s1,
    const float* __restrict__ s2, const float* __restrict__ s3,
    const float* __restrict__ s4, const float* __restrict__ s5,
    const float* __restrict__ s6, const float* __restrict__ s7,
    u16* __restrict__ d0, u16* __restrict__ d1, u16* __restrict__ d2,
    u16* __restrict__ d3, u16* __restrict__ d4, u16* __restrict__ d5,
    u16* __restrict__ d6, u16* __restrict__ d7, float* __restrict__ sums) {
  if (blockIdx.x == 0) {
#pragma unroll
    for (int i = 0; i < 32; i++) sums[threadIdx.x + i * 256] = 0.f;
  }
  const unsigned base = blockIdx.x * 1024u;
  const float* src;
  u16* dst;
  unsigned off;
  if (base < 16777216u)      { src = s0; dst = d0; off = 0u; }
  else if (base < 17301504u) { src = s1; dst = d1; off = 16777216u; }
  else if (base < 18350080u) { src = s2; dst = d2; off = 17301504u; }
  else if (base < 19398656u) { src = s3; dst = d3; off = 18350080u; }
  else if (base < 20447232u) { src = s4; dst = d4; off = 19398656u; }
  else if (base < 21495808u) { src = s5; dst = d5; off = 20447232u; }
  else if (base < 25690112u) { src = s6; dst = d6; off = 21495808u; }
  else                       { src = s7; dst = d7; off = 25690112u; }
  const unsigned i = base - off + threadIdx.x * 4u;
  float4 v = *reinterpret_cast<const float4*>(src + i);
  ushort4 o;
  o.x = f2b(v.x); o.y = f2b(v.y); o.z = f2b(v.z); o.w = f2b(v.w);
  *reinterpret_cast<ushort4*>(dst + i) = o;
}

// ---------------- cast + transpose x3: out[z][i][j] = bf16(in_z[j][i]), 1024x1024 ----------------
__global__ __launch_bounds__(256) void castT3_kernel(const float* __restrict__ s0,
                                                     const float* __restrict__ s1,
                                                     const float* __restrict__ s2,
                                                     u16* __restrict__ out) {
  __shared__ u16 sm[32][33];
  const float* in = blockIdx.z == 0 ? s0 : (blockIdx.z == 1 ? s1 : s2);
  u16* o = out + (size_t)blockIdx.z * 1048576;
  const int r0 = blockIdx.y * 32, c0 = blockIdx.x * 32;
  const int t = threadIdx.x;
  const int r = t >> 3, c4 = (t & 7) * 4;
  float4 v = *reinterpret_cast<const float4*>(in + (size_t)(r0 + r) * 1024 + c0 + c4);
  sm[c4 + 0][r] = f2b(v.x);
  sm[c4 + 1][r] = f2b(v.y);
  sm[c4 + 2][r] = f2b(v.z);
  sm[c4 + 3][r] = f2b(v.w);
  __syncthreads();
  ushort4 q;
  q.x = sm[r][c4 + 0]; q.y = sm[r][c4 + 1]; q.z = sm[r][c4 + 2]; q.w = sm[r][c4 + 3];
  *reinterpret_cast<ushort4*>(o + (size_t)(c0 + r) * 1024 + r0 + c4) = q;
}

// ---------------- bias compose x3: out[sel][o] = dot(A_sel[o,:], b_sel) + c_sel[o] ----------------
__global__ __launch_bounds__(256) void biascomp3_kernel(
    const float* __restrict__ A0, const float* __restrict__ A1, const float* __restrict__ A2,
    const float* __restrict__ b0, const float* __restrict__ b1, const float* __restrict__ b2,
    const float* __restrict__ c0, const float* __restrict__ c1, const float* __restrict__ c2,
    float* __restrict__ out) {
  __shared__ float red[4];
  const int sel = blockIdx.x >> 10;
  const int row = blockIdx.x & 1023;
  const float* A = sel == 0 ? A0 : (sel == 1 ? A1 : A2);
  const float* b = sel == 0 ? b0 : (sel == 1 ? b1 : b2);
  const float* c = sel == 0 ? c0 : (sel == 1 ? c1 : c2);
  const int t = threadIdx.x;
  float4 va = *reinterpret_cast<const float4*>(A + (size_t)row * 1024 + t * 4);
  float4 vb = *reinterpret_cast<const float4*>(b + t * 4);
  float s = va.x * vb.x + va.y * vb.y + va.z * vb.z + va.w * vb.w;
  s = wave_red(s);
  if ((t & 63) == 0) red[t >> 6] = s;
  __syncthreads();
  if (t == 0) out[sel * 1024 + row] = red[0] + red[1] + red[2] + red[3] + c[row];
}

// ---------------- 128x128 GEMM (kept for the 1024^3 z=3 composition) ----------------
template <int EPI, int BIASM, int SWZ>
__global__ __launch_bounds__(256) void gemm_bt(
    const u16* __restrict__ A, const u16* __restrict__ W, const float* __restrict__ bias,
    void* __restrict__ Cout, int M, int N, int K, int lda, int ldw, int ldc,
    long long bsA, long long bsW, long long bsC) {
  __shared__ u16 a_sm[128 * 32];
  __shared__ u16 b_sm[128 * 32];
  int bx = blockIdx.x, by = blockIdx.y, bz = blockIdx.z;
  if (SWZ) {
    const int gx = gridDim.x, gy = gridDim.y;
    const int lin = bx + gx * (by + gy * bz);
    const int nwg = gx * gy * gridDim.z;
    const int swz = (lin & 7) * (nwg >> 3) + (lin >> 3);
    bx = swz % gx;
    const int t2 = swz / gx;
    by = t2 % gy;
    bz = t2 / gy;
  }
  const int t = threadIdx.x;
  const int lane = t & 63;
  const int wv = t >> 6;
  const int wm = wv >> 1, wn = wv & 1;
  const int l15 = lane & 15, l4 = lane >> 4;
  const long long zb = bz;

  const u16* Ab = A + zb * bsA;
  const u16* Wb = W + zb * bsW;

  const u16* ag = Ab + (size_t)(by * 128 + (t >> 2)) * lda + (t & 3) * 8;
  const u16* wg = Wb + (size_t)(bx * 128 + (t >> 2)) * ldw + (t & 3) * 8;
  u16* ad = a_sm + t * 8;
  u16* bd = b_sm + t * 8;

  f32x4 acc[4][4] = {};

  for (int k0 = 0; k0 < K; k0 += 32) {
    gld16(ag, ad);
    gld16(ag + (size_t)64 * lda, ad + 64 * 32);
    gld16(wg, bd);
    gld16(wg + (size_t)64 * ldw, bd + 64 * 32);
    ag += 32; wg += 32;
    __syncthreads();
    bf16x8 af[4], bf[4];
#pragma unroll
    for (int m = 0; m < 4; m++)
      af[m] = *reinterpret_cast<const bf16x8*>(&a_sm[(wm * 64 + m * 16 + l15) * 32 + l4 * 8]);
#pragma unroll
    for (int n = 0; n < 4; n++)
      bf[n] = *reinterpret_cast<const bf16x8*>(&b_sm[(wn * 64 + n * 16 + l15) * 32 + l4 * 8]);
#pragma unroll
    for (int m = 0; m < 4; m++)
#pragma unroll
      for (int n = 0; n < 4; n++)
        acc[m][n] = MFMA16(af[m], bf[n], acc[m][n]);
    __syncthreads();
  }

  const int gm0 = by * 128 + wm * 64;
  const int gn0 = bx * 128 + wn * 64;
  float* cf = reinterpret_cast<float*>(Cout) + zb * bsC;
  u16* cb = reinterpret_cast<u16*>(Cout) + zb * bsC;
#pragma unroll
  for (int m = 0; m < 4; m++) {
#pragma unroll
    for (int n = 0; n < 4; n++) {
      const int col = gn0 + n * 16 + l15;
      float bc = (BIASM == 1) ? bias[col] : 0.f;
#pragma unroll
      for (int r = 0; r < 4; r++) {
        const int row = gm0 + m * 16 + l4 * 4 + r;
        float v = acc[m][n][r];
        if (BIASM == 1) v += bc;
        if (BIASM == 2) v += bias[row];
        if (EPI == 2) v = 0.5f * v * (1.0f + erff(v * 0.70710678118654752f));
        if (EPI == 0) cf[(size_t)row * ldc + col] = v;
        else          cb[(size_t)row * ldc + col] = f2b(v);
      }
    }
  }
}

// ---------------- 256x256 8-phase deep-pipelined GEMM (bf16 out) ----------------
// C[m,n] = sum_k A[m,k]*W[n,k] + bias ; BIASM: 1 = bias[col], 2 = bias[row]
// grid (N/256, M/256, Z), 512 threads. K % 64 == 0. nwg % 8 == 0.
template <int BIASM>
__global__ __launch_bounds__(512, 2) void gemm8p(
    const u16* __restrict__ A, const u16* __restrict__ W, const float* __restrict__ bias,
    u16* __restrict__ Cout, int K, int lda, int ldw, int ldc,
    long long bsA, long long bsW, long long bsC) {
  __shared__ u16 lds[2][2][256 * 64];  // [dbuf][A/B][row][64 cols]
  int bx = blockIdx.x, by = blockIdx.y, bz = blockIdx.z;
  {
    const int gx = gridDim.x, gy = gridDim.y;
    const int lin = bx + gx * (by + gy * bz);
    const int nwg = gx * gy * gridDim.z;
    const int swz = (lin & 7) * (nwg >> 3) + (lin >> 3);
    bx = swz % gx;
    const int t2 = swz / gx;
    by = t2 % gy;
    bz = t2 / gy;
  }
  const int t = threadIdx.x;
  const int lane = t & 63;
  const int w = t >> 6;          // wave 0..7
  const int wm = w >> 2;         // 0..1 (M half)
  const int wn = w & 3;          // 0..3 (N quarter)
  const int l15 = lane & 15, l4 = lane >> 4;
  const long long zb = bz;
  const u16* Ab = A + zb * bsA;
  const u16* Wb = W + zb * bsW;

  // staging: wave stages the A-half (rows wm*128..+128) and B-half (rows (wn>>1)*128..+128)
  // it consumes; each half split 4 ways among its 4 consumer waves, 4 ops of 1KB each.
  const int lr = lane >> 3;      // row within 8-row group
  const int lc = lane & 7;       // 16B chunk
  const int scs = lc ^ lr;       // inverse-swizzled source chunk (rule #21)
  const int arow_base = wm * 128 + wn * 32;                      // A local rows staged
  const int brow_base = (wn >> 1) * 128 + (wm * 2 + (wn & 1)) * 32;  // B local rows staged

  const u16* ag = Ab + (size_t)(by * 256 + arow_base + lr) * lda + scs * 8;
  const u16* wg = Wb + (size_t)(bx * 256 + brow_base + lr) * ldw + scs * 8;

  f32x4 acc[8][4] = {};
  const int NT = K >> 6;

  // prologue: stage tile 0 into buf 0
#pragma unroll
  for (int j = 0; j < 4; j++) {
    gld16(ag + (size_t)(j * 8) * lda, &lds[0][0][(arow_base + j * 8) * 64] + lane * 8);
    gld16(wg + (size_t)(j * 8) * ldw, &lds[0][1][(brow_base + j * 8) * 64] + lane * 8);
  }
  asm volatile("s_waitcnt vmcnt(0)" ::: "memory");
  __builtin_amdgcn_s_barrier();

  for (int kt = 0; kt < NT; kt++) {
    const int cur = kt & 1;
    // early issue: stage tile kt+1 into the other buffer (~4 phases of latency lead)
    if (kt + 1 < NT) {
      const int k0n = (kt + 1) << 6;
#pragma unroll
      for (int j = 0; j < 4; j++) {
        gld16(ag + (size_t)(j * 8) * lda + k0n,
              &lds[cur ^ 1][0][(arow_base + j * 8) * 64] + lane * 8);
        gld16(wg + (size_t)(j * 8) * ldw + k0n,
              &lds[cur ^ 1][1][(brow_base + j * 8) * 64] + lane * 8);
      }
    }
    const u16* As = &lds[cur][0][0];
    const u16* Bs = &lds[cur][1][0];
    bf16x8 afr[8], bfr[4];
#pragma unroll
    for (int kh = 0; kh < 2; kh++) {
      // phase a: read A frags (8) + B frags n0..1, MFMA quadrant (all m, n0..1)
#pragma unroll
      for (int mi = 0; mi < 8; mi++) {
        const int ra = wm * 128 + mi * 16 + l15;
        afr[mi] = *reinterpret_cast<const bf16x8*>(
            &As[ra * 64 + (((kh * 4 + l4) ^ (ra & 7)) * 8)]);
      }
#pragma unroll
      for (int ni = 0; ni < 2; ni++) {
        const int rb = wn * 64 + ni * 16 + l15;
        bfr[ni] = *reinterpret_cast<const bf16x8*>(
            &Bs[rb * 64 + (((kh * 4 + l4) ^ (rb & 7)) * 8)]);
      }
      __builtin_amdgcn_s_setprio(1);
#pragma unroll
      for (int mi = 0; mi < 8; mi++) {
        acc[mi][0] = MFMA16(afr[mi], bfr[0], acc[mi][0]);
        acc[mi][1] = MFMA16(afr[mi], bfr[1], acc[mi][1]);
      }
      __builtin_amdgcn_s_setprio(0);
      __builtin_amdgcn_s_barrier();
      // phase b: read B frags n2..3, MFMA quadrant (all m, n2..3)
#pragma unroll
      for (int ni = 0; ni < 2; ni++) {
        const int rb = wn * 64 + (ni + 2) * 16 + l15;
        bfr[2 + ni] = *reinterpret_cast<const bf16x8*>(
            &Bs[rb * 64 + (((kh * 4 + l4) ^ (rb & 7)) * 8)]);
      }
      __builtin_amdgcn_s_setprio(1);
#pragma unroll
      for (int mi = 0; mi < 8; mi++) {
        acc[mi][2] = MFMA16(afr[mi], bfr[2], acc[mi][2]);
        acc[mi][3] = MFMA16(afr[mi], bfr[3], acc[mi][3]);
      }
      __builtin_amdgcn_s_setprio(0);
      __builtin_amdgcn_s_barrier();
    }
    // tile boundary: drain staging (issued ~4 phases ago), then sync
    if (kt + 1 < NT) {
      asm volatile("s_waitcnt vmcnt(0)" ::: "memory");
      __builtin_amdgcn_sched_barrier(0);
    }
    __builtin_amdgcn_s_barrier();
  }

  const int gm0 = by * 256 + wm * 128;
  const int gn0 = bx * 256 + wn * 64;
  u16* cb = Cout + zb * bsC;
#pragma unroll
  for (int mi = 0; mi < 8; mi++) {
#pragma unroll
    for (int ni = 0; ni < 4; ni++) {
      const int col = gn0 + ni * 16 + l15;
      float bc = (BIASM == 1) ? bias[col] : 0.f;
#pragma unroll
      for (int r = 0; r < 4; r++) {
        const int row = gm0 + mi * 16 + l4 * 4 + r;
        float v = acc[mi][ni][r] + ((BIASM == 1) ? bc : bias[row]);
        cb[(size_t)row * ldc + col] = f2b(v);
      }
    }
  }
}

// ---------------- 64x64 GEMM (small-shape variant) ----------------
template <int EPI, int BIASM>
__global__ __launch_bounds__(256) void gemm64(
    const u16* __restrict__ A, const u16* __restrict__ W, const float* __restrict__ bias,
    void* __restrict__ Cout, int M, int N, int K, int lda, int ldw, int ldc) {
  __shared__ u16 a_sm[64 * 32];
  __shared__ u16 b_sm[64 * 32];
  const int t = threadIdx.x;
  const int lane = t & 63;
  const int wv = t >> 6;
  const int wm = wv >> 1, wn = wv & 1;
  const int l15 = lane & 15, l4 = lane >> 4;

  const u16* ag = A + (size_t)(blockIdx.y * 64 + (t >> 2)) * lda + (t & 3) * 8;
  const u16* wg = W + (size_t)(blockIdx.x * 64 + (t >> 2)) * ldw + (t & 3) * 8;
  u16* ad = a_sm + t * 8;
  u16* bd = b_sm + t * 8;

  f32x4 acc[2][2] = {};

  for (int k0 = 0; k0 < K; k0 += 32) {
    gld16(ag, ad);
    gld16(wg, bd);
    ag += 32; wg += 32;
    __syncthreads();
    bf16x8 af[2], bf[2];
#pragma unroll
    for (int m = 0; m < 2; m++)
      af[m] = *reinterpret_cast<const bf16x8*>(&a_sm[(wm * 32 + m * 16 + l15) * 32 + l4 * 8]);
#pragma unroll
    for (int n = 0; n < 2; n++)
      bf[n] = *reinterpret_cast<const bf16x8*>(&b_sm[(wn * 32 + n * 16 + l15) * 32 + l4 * 8]);
#pragma unroll
    for (int m = 0; m < 2; m++)
#pragma unroll
      for (int n = 0; n < 2; n++)
        acc[m][n] = MFMA16(af[m], bf[n], acc[m][n]);
    __syncthreads();
  }

  const int gm0 = blockIdx.y * 64 + wm * 32;
  const int gn0 = blockIdx.x * 64 + wn * 32;
  float* cf = reinterpret_cast<float*>(Cout);
  u16* cb = reinterpret_cast<u16*>(Cout);
#pragma unroll
  for (int m = 0; m < 2; m++) {
#pragma unroll
    for (int n = 0; n < 2; n++) {
      const int col = gn0 + n * 16 + l15;
      float bc = (BIASM == 1) ? bias[col] : 0.f;
#pragma unroll
      for (int r = 0; r < 4; r++) {
        const int row = gm0 + m * 16 + l4 * 4 + r;
        float v = acc[m][n][r];
        if (BIASM == 1) v += bc;
        if (BIASM == 2) v += bias[row];
        if (EPI == 2) v = 0.5f * v * (1.0f + erff(v * 0.70710678118654752f));
        if (EPI == 0) cf[(size_t)row * ldc + col] = v;
        else          cb[(size_t)row * ldc + col] = f2b(v);
      }
    }
  }
}

// ---------------- 64x64 split-K GEMM -> f32 partials ----------------
__global__ __launch_bounds__(256) void gemm64sk(
    const u16* __restrict__ A, const u16* __restrict__ W, float* __restrict__ part,
    int N, int Kc, int lda, int ldw) {
  __shared__ u16 a_sm[64 * 32];
  __shared__ u16 b_sm[64 * 32];
  const int t = threadIdx.x;
  const int lane = t & 63;
  const int wv = t >> 6;
  const int wm = wv >> 1, wn = wv & 1;
  const int l15 = lane & 15, l4 = lane >> 4;
  const int z = blockIdx.z;

  const u16* ag = A + (size_t)(blockIdx.y * 64 + (t >> 2)) * lda + z * Kc + (t & 3) * 8;
  const u16* wg = W + (size_t)(blockIdx.x * 64 + (t >> 2)) * ldw + z * Kc + (t & 3) * 8;
  u16* ad = a_sm + t * 8;
  u16* bd = b_sm + t * 8;

  f32x4 acc[2][2] = {};

  for (int k0 = 0; k0 < Kc; k0 += 32) {
    gld16(ag, ad);
    gld16(wg, bd);
    ag += 32; wg += 32;
    __syncthreads();
    bf16x8 af[2], bf[2];
#pragma unroll
    for (int m = 0; m < 2; m++)
      af[m] = *reinterpret_cast<const bf16x8*>(&a_sm[(wm * 32 + m * 16 + l15) * 32 + l4 * 8]);
#pragma unroll
    for (int n = 0; n < 2; n++)
      bf[n] = *reinterpret_cast<const bf16x8*>(&b_sm[(wn * 32 + n * 16 + l15) * 32 + l4 * 8]);
#pragma unroll
    for (int m = 0; m < 2; m++)
#pragma unroll
      for (int n = 0; n < 2; n++)
        acc[m][n] = MFMA16(af[m], bf[n], acc[m][n]);
    __syncthreads();
  }

  const int Mtot = gridDim.y * 64;
  float* po = part + (size_t)z * Mtot * N;
  const int gm0 = blockIdx.y * 64 + wm * 32;
  const int gn0 = blockIdx.x * 64 + wn * 32;
#pragma unroll
  for (int m = 0; m < 2; m++) {
#pragma unroll
    for (int n = 0; n < 2; n++) {
      const int col = gn0 + n * 16 + l15;
#pragma unroll
      for (int r = 0; r < 4; r++) {
        const int row = gm0 + m * 16 + l4 * 4 + r;
        po[(size_t)row * N + col] = acc[m][n][r];
      }
    }
  }
}

// ---------------- reduce 2 partials + bias -> bf16 (512x1024) ----------------
__global__ __launch_bounds__(256) void redb_kernel(const float* __restrict__ p,
                                                   const float* __restrict__ bias,
                                                   u16* __restrict__ out) {
  const int i = (blockIdx.x * 256 + threadIdx.x) * 4;
  const int col = i & 1023;
  float4 v0 = *reinterpret_cast<const float4*>(p + i);
  float4 v1 = *reinterpret_cast<const float4*>(p + 524288 + i);
  float4 vb = *reinterpret_cast<const float4*>(bias + col);
  ushort4 o;
  o.x = f2b(v0.x + v1.x + vb.x);
  o.y = f2b(v0.y + v1.y + vb.y);
  o.z = f2b(v0.z + v1.z + vb.z);
  o.w = f2b(v0.w + v1.w + vb.w);
  *reinterpret_cast<ushort4*>(out + i) = o;
}

// ---------------- scores: probs = exp(QK^T/8) (masked->0) + fused row-sum atomics ----------------
__global__ __launch_bounds__(256) void scores_kernel(const u16* __restrict__ QH,
                                                     const u16* __restrict__ KH,
                                                     const int* __restrict__ mask,
                                                     u16* __restrict__ probs,
                                                     float* __restrict__ sums) {
  __shared__ u16 q_sm[64 * 64];
  __shared__ u16 k_sm[256 * 64];
  __shared__ float srs[64];
  int bx = blockIdx.x, by = blockIdx.y;
  {
    const int lin = bx + 8 * by;
    const int swz = (lin & 7) * 128 + (lin >> 3);
    bx = swz & 7;
    by = swz >> 3;
  }
  const int bh = by;
  const int b = bh >> 4, h = bh & 15;
  const int sc = bx;
  const int t = threadIdx.x;
  const int lane = t & 63;
  const int wv = t >> 6;
  const int l15 = lane & 15, l4 = lane >> 4;
  const int x7 = l15 & 7;

  const int r = t >> 3;
  const int cs = (t & 7) ^ (r & 7);
  {
    const u16* src = QH + (size_t)(b * 64 + r) * 1024 + h * 64 + cs * 8;
    u16* dst = q_sm + t * 8;
    gld16(src, dst);
    gld16(src + (size_t)32 * 1024, dst + 32 * 64);
  }
  {
    const u16* src = KH + (size_t)(b * 2048 + sc * 256 + r) * 1024 + h * 64 + cs * 8;
    u16* dst = k_sm + t * 8;
#pragma unroll
    for (int i = 0; i < 8; i++)
      gld16(src + (size_t)i * 32 * 1024, dst + i * 32 * 64);
  }
  if (t < 64) srs[t] = 0.f;
  __syncthreads();

  f32x4 acc[4][4] = {};
#pragma unroll
  for (int ks = 0; ks < 2; ks++) {
    bf16x8 af[4], bf[4];
#pragma unroll
    for (int m = 0; m < 4; m++)
      af[m] = *reinterpret_cast<const bf16x8*>(
          &q_sm[(m * 16 + l15) * 64 + ((ks * 4 + l4) ^ x7) * 8]);
#pragma unroll
    for (int n = 0; n < 4; n++)
      bf[n] = *reinterpret_cast<const bf16x8*>(
          &k_sm[(wv * 64 + n * 16 + l15) * 64 + ((ks * 4 + l4) ^ x7) * 8]);
#pragma unroll
    for (int m = 0; m < 4; m++)
#pragma unroll
      for (int n = 0; n < 4; n++)
        acc[m][n] = MFMA16(af[m], bf[n], acc[m][n]);
  }

  float rs[4][4] = {};
#pragma unroll
  for (int n = 0; n < 4; n++) {
    const int sg = sc * 256 + wv * 64 + n * 16 + l15;
    const bool keep = mask[b * 2048 + sg] != 0;
#pragma unroll
    for (int m = 0; m < 4; m++) {
#pragma unroll
      for (int r2 = 0; r2 < 4; r2++) {
        const int row = m * 16 + l4 * 4 + r2;
        float p = keep ? __expf(acc[m][n][r2] * 0.125f) : 0.f;
        probs[((size_t)bh * 64 + row) * 2048 + sg] = f2b(p);
        rs[m][r2] += p;
      }
    }
  }
  // reduce across the 16-lane (l15) group, accumulate per-row into LDS, then global
#pragma unroll
  for (int m = 0; m < 4; m++)
#pragma unroll
    for (int r2 = 0; r2 < 4; r2++) {
      float v = rs[m][r2];
      v += __shfl_xor(v, 1);
      v += __shfl_xor(v, 2);
      v += __shfl_xor(v, 4);
      v += __shfl_xor(v, 8);
      rs[m][r2] = v;
    }
  if (l15 == 0) {
#pragma unroll
    for (int m = 0; m < 4; m++)
#pragma unroll
      for (int r2 = 0; r2 < 4; r2++)
        atomicAdd(&srs[m * 16 + l4 * 4 + r2], rs[m][r2]);
  }
  __syncthreads();
  if (t < 64) atomicAdd(&sums[bh * 64 + t], srs[t]);
}

// ---------------- PV split-K partials (LDS-swizzled) ----------------
__global__ __launch_bounds__(256) void pv_part_kernel(const u16* __restrict__ probs,
                                                      const u16* __restrict__ VT,
                                                      float* __restrict__ part) {
  __shared__ u16 a_sm[64 * 64];
  __shared__ u16 b_sm[64 * 64];
  int bx = blockIdx.x, by = blockIdx.y;
  {
    const int lin = bx + 4 * by;
    const int swz = (lin & 7) * 64 + (lin >> 3);
    bx = swz & 3;
    by = swz >> 2;
  }
  const int c = bx;
  const int bh = by;
  const int b = bh >> 4, h = bh & 15;
  const u16* Ab = probs + (size_t)bh * 64 * 2048;
  const u16* Bb = VT + ((size_t)b * 1024 + h * 64) * 2048;
  const int t = threadIdx.x;
  const int lane = t & 63;
  const int wv = t >> 6;
  const int wm = wv >> 1, wn = wv & 1;
  const int l15 = lane & 15, l4 = lane >> 4;
  const int x7 = l15 & 7;

  const int r = t >> 3;
  const int cs = (t & 7) ^ (r & 7);

  f32x4 acc[2][2] = {};
  for (int k0 = c * 512; k0 < c * 512 + 512; k0 += 64) {
    const u16* as = Ab + (size_t)r * 2048 + k0 + cs * 8;
    const u16* bs = Bb + (size_t)r * 2048 + k0 + cs * 8;
    u16* ad = a_sm + t * 8;
    u16* bd = b_sm + t * 8;
    gld16(as, ad);
    gld16(as + (size_t)32 * 2048, ad + 32 * 64);
    gld16(bs, bd);
    gld16(bs + (size_t)32 * 2048, bd + 32 * 64);
    __syncthreads();
#pragma unroll
    for (int ks = 0; ks < 2; ks++) {
      bf16x8 af[2], bf[2];
#pragma unroll
      for (int m = 0; m < 2; m++)
        af[m] = *reinterpret_cast<const bf16x8*>(
            &a_sm[(wm * 32 + m * 16 + l15) * 64 + ((ks * 4 + l4) ^ x7) * 8]);
#pragma unroll
      for (int n = 0; n < 2; n++)
        bf[n] = *reinterpret_cast<const bf16x8*>(
            &b_sm[(wn * 32 + n * 16 + l15) * 64 + ((ks * 4 + l4) ^ x7) * 8]);
#pragma unroll
      for (int m = 0; m < 2; m++)
#pragma unroll
        for (int n = 0; n < 2; n++)
          acc[m][n] = MFMA16(af[m], bf[n], acc[m][n]);
    }
    __syncthreads();
  }

  float* po = part + ((size_t)(bh * 4 + c)) * 4096;
#pragma unroll
  for (int m = 0; m < 2; m++) {
#pragma unroll
    for (int n = 0; n < 2; n++) {
#pragma unroll
      for (int r2 = 0; r2 < 4; r2++) {
        const int l = wm * 32 + m * 16 + l4 * 4 + r2;
        const int hd = wn * 32 + n * 16 + l15;
        po[l * 64 + hd] = acc[m][n][r2];
      }
    }
  }
}

// ---------------- PV reduce: attn = (sum_c part) / rowsum ----------------
__global__ __launch_bounds__(256) void pv_reduce_kernel(const float* __restrict__ part,
                                                        const float* __restrict__ sums,
                                                        u16* __restrict__ attn) {
  const int t = threadIdx.x;
  const int e0 = (blockIdx.x * 256 + t) * 4;
  const int bh = e0 >> 12;
  const int r = e0 & 4095;
  const int l = r >> 6, hd = r & 63;
  const int b = bh >> 4, h = bh & 15;
  const float* p = part + ((size_t)bh * 4) * 4096 + r;
  float4 v0 = *reinterpret_cast<const float4*>(p);
  float4 v1 = *reinterpret_cast<const float4*>(p + 4096);
  float4 v2 = *reinterpret_cast<const float4*>(p + 8192);
  float4 v3 = *reinterpret_cast<const float4*>(p + 12288);
  const float sc = 1.0f / sums[bh * 64 + l];
  ushort4 o;
  o.x = f2b((v0.x + v1.x + v2.x + v3.x) * sc);
  o.y = f2b((v0.y + v1.y + v2.y + v3.y) * sc);
  o.z = f2b((v0.z + v1.z + v2.z + v3.z) * sc);
  o.w = f2b((v0.w + v1.w + v2.w + v3.w) * sc);
  *reinterpret_cast<ushort4*>(attn + (size_t)(b * 64 + l) * 1024 + h * 64 + hd) = o;
}

// ---------------- head-mean of normalized probs -> attn_weights [B,L,S] f32 ----------------
__global__ __launch_bounds__(256) void mean_kernel(const u16* __restrict__ probs,
                                                   const float* __restrict__ sums,
                                                   float* __restrict__ outw) {
  __shared__ float s_inv[16];
  const int bl = blockIdx.x;
  const int b = bl >> 6, l = bl & 63;
  const int t = threadIdx.x;
  if (t < 16) s_inv[t] = 0.0625f / sums[(b * 16 + t) * 64 + l];
  __syncthreads();
  float av[8] = {0.f, 0.f, 0.f, 0.f, 0.f, 0.f, 0.f, 0.f};
  for (int h = 0; h < 16; h++) {
    uint4 r4 = *reinterpret_cast<const uint4*>(
        probs + ((size_t)((b * 16 + h) * 64 + l)) * 2048 + t * 8);
    float sc = s_inv[h];
    av[0] += b2f((u16)(r4.x & 0xffffu)) * sc; av[1] += b2f((u16)(r4.x >> 16)) * sc;
    av[2] += b2f((u16)(r4.y & 0xffffu)) * sc; av[3] += b2f((u16)(r4.y >> 16)) * sc;
    av[4] += b2f((u16)(r4.z & 0xffffu)) * sc; av[5] += b2f((u16)(r4.z >> 16)) * sc;
    av[6] += b2f((u16)(r4.w & 0xffffu)) * sc; av[7] += b2f((u16)(r4.w >> 16)) * sc;
  }
  float* o = outw + (size_t)bl * 2048 + t * 8;
  *reinterpret_cast<float4*>(o) = make_float4(av[0], av[1], av[2], av[3]);
  *reinterpret_cast<float4*>(o + 4) = make_float4(av[4], av[5], av[6], av[7]);
}

// ---------------- LayerNorm with NP f32 partial addends + bias ----------------
template <int NP>
__global__ __launch_bounds__(256) void lnp_kernel(const float* __restrict__ a,
                                                  const float* __restrict__ parts,
                                                  const float* __restrict__ bias,
                                                  const float* __restrict__ g,
                                                  const float* __restrict__ bet,
                                                  float* __restrict__ outf,
                                                  u16* __restrict__ outb) {
  __shared__ float red[8];
  __shared__ float mv[2];
  const int row = blockIdx.x;
  const int t = threadIdx.x;
  const size_t idx = (size_t)row * 1024 + t * 4;
  const float4 va = *reinterpret_cast<const float4*>(a + idx);
  const float4 vb = *reinterpret_cast<const float4*>(bias + t * 4);
  float x0 = va.x + vb.x, x1 = va.y + vb.y, x2 = va.z + vb.z, x3 = va.w + vb.w;
#pragma unroll
  for (int p = 0; p < NP; p++) {
    const float4 vp = *reinterpret_cast<const float4*>(parts + (size_t)p * 524288 + idx);
    x0 += vp.x; x1 += vp.y; x2 += vp.z; x3 += vp.w;
  }
  float s = x0 + x1 + x2 + x3;
  float q = x0 * x0 + x1 * x1 + x2 * x2 + x3 * x3;
  s = wave_red(s);
  q = wave_red(q);
  if ((t & 63) == 0) { red[t >> 6] = s; red[4 + (t >> 6)] = q; }
  __syncthreads();
  if (t == 0) {
    float S = red[0] + red[1] + red[2] + red[3];
    float Q = red[4] + red[5] + red[6] + red[7];
    float mu = S * (1.f / 1024.f);
    float var = Q * (1.f / 1024.f) - mu * mu;
    mv[0] = mu;
    mv[1] = rsqrtf(var + 1e-5f);
  }
  __syncthreads();
  const float mu = mv[0], rs = mv[1];
  const float4 vg = *reinterpret_cast<const float4*>(g + t * 4);
  const float4 ve = *reinterpret_cast<const float4*>(bet + t * 4);
  float y0 = (x0 - mu) * rs * vg.x + ve.x;
  float y1 = (x1 - mu) * rs * vg.y + ve.y;
  float y2 = (x2 - mu) * rs * vg.z + ve.z;
  float y3 = (x3 - mu) * rs * vg.w + ve.w;
  *reinterpret_cast<float4*>(outf + idx) = make_float4(y0, y1, y2, y3);
  if (outb) {
    ushort4 o;
    o.x = f2b(y0); o.y = f2b(y1); o.z = f2b(y2); o.w = f2b(y3);
    *reinterpret_cast<ushort4*>(outb + idx) = o;
  }
}

extern "C" void kernel_launch(void* const* d_in, const int* in_sizes, int n_in,
                              void* d_out, int out_size, void* d_ws, size_t ws_size,
                              hipStream_t stream) {
  const float* latents = (const float*)d_in[0];
  const float* context = (const float*)d_in[1];
  const int* cmask = (const int*)d_in[2];
  const float* q_w = (const float*)d_in[3];   const float* q_b = (const float*)d_in[4];
  const float* k_w = (const float*)d_in[5];   const float* k_b = (const float*)d_in[6];
  const float* v_w = (const float*)d_in[7];   const float* v_b = (const float*)d_in[8];
  const float* in_wq = (const float*)d_in[9]; const float* in_bq = (const float*)d_in[10];
  const float* in_wk = (const float*)d_in[11]; const float* in_bk = (const float*)d_in[12];
  const float* in_wv = (const float*)d_in[13]; const float* in_bv = (const float*)d_in[14];
  const float* out_w = (const float*)d_in[15]; const float* out_b = (const float*)d_in[16];
  const float* ln1_g = (const float*)d_in[17]; const float* ln1_b = (const float*)d_in[18];
  const float* ln2_g = (const float*)d_in[19]; const float* ln2_b = (const float*)d_in[20];
  const float* ff_w1 = (const float*)d_in[21]; const float* ff_b1 = (const float*)d_in[22];
  const float* ff_w2 = (const float*)d_in[23]; const float* ff_b2 = (const float*)d_in[24];

  char* wsb = (char*)d_ws;
  size_t off = 0;
  auto alloc = [&](size_t bytes) -> char* {
    char* p = wsb + off;
    off = (off + bytes + 255) & ~(size_t)255;
    return p;
  };

  u16* ctx_b = (u16*)alloc(33554432);   // [16384,1024] bf16; region reused later
  u16* kh    = (u16*)alloc(33554432);   // [16384,1024] bf16 (KH)
  u16* vt    = (u16*)alloc(33554432);   // [8][1024][2048] bf16 (V^T per batch)
  u16* probs = (u16*)alloc(33554432);   // [128][64][2048] bf16
  float* pvp = (float*)alloc(8388608);  // [128][4][4096] f32 PV partials
  u16* lat_b = (u16*)alloc(1048576);
  u16* wiq   = (u16*)alloc(2097152);
  u16* wik   = (u16*)alloc(2097152);
  u16* wiv   = (u16*)alloc(2097152);
  u16* qwT   = (u16*)alloc(2097152);    // qwT/kwT/vwT contiguous
  u16* kwT   = (u16*)alloc(2097152);
  u16* vwT   = (u16*)alloc(2097152);
  u16* wqc   = (u16*)alloc(2097152);    // wqc/wkc/wvc contiguous
  u16* wkc   = (u16*)alloc(2097152);
  u16* wvc   = (u16*)alloc(2097152);
  u16* wob   = (u16*)alloc(2097152);
  u16* wf1b  = (u16*)alloc(8388608);
  u16* wf2b  = (u16*)alloc(8388608);
  float* b_qc = (float*)alloc(4096);    // b_qc/b_kc/b_vc contiguous
  float* b_kc = (float*)alloc(4096);
  float* b_vc = (float*)alloc(4096);
  float* sums = (float*)alloc(32768);
  float* partsQ = (float*)alloc(4194304);   // 2 x [512,1024] f32
  float* partsO = (float*)alloc(4194304);   // 2 x [512,1024] f32
  float* partsF = (float*)alloc(16777216);  // 4 x [512,1024] f32

  // aliases into ctx_b region (dead after the VT GEMM)
  char* ar = (char*)ctx_b;
  u16* qhb    = (u16*)(ar);               // 1 MB
  u16* attn_b = (u16*)(ar + 1048576);     // 1 MB
  u16* xb     = (u16*)(ar + 2097152);     // 1 MB
  u16* h1     = (u16*)(ar + 3145728);     // 4 MB
  float* xf   = (float*)(ar + 7340032);   // 2 MB

  // ---- fused casts (+ zero sums) ----
  fused_cast_kernel<<<dim3(29184), 256, 0, stream>>>(
      context, latents, in_wq, in_wk, in_wv, out_w, ff_w1, ff_w2,
      ctx_b, lat_b, wiq, wik, wiv, wob, wf1b, wf2b, sums);

  // ---- cast+transpose external weights (batched) ----
  castT3_kernel<<<dim3(32, 32, 3), 256, 0, stream>>>(q_w, k_w, v_w, qwT);

  // ---- composed biases (batched) ----
  biascomp3_kernel<<<dim3(3072), 256, 0, stream>>>(in_wq, in_wk, in_wv,
                                                   q_b, k_b, v_b,
                                                   in_bq, in_bk, in_bv, b_qc);

  // ---- composed weights, batched z=3 ----
  gemm_bt<1, 0, 1><<<dim3(8, 8, 3), 256, 0, stream>>>(wiq, qwT, nullptr, wqc,
      1024, 1024, 1024, 1024, 1024, 1024, 1048576, 1048576, 1048576);

  // ---- KH = ctx * Wkc^T + b_kc  [16384,1024]  (8-phase 256^2) ----
  gemm8p<1><<<dim3(4, 64, 1), 512, 0, stream>>>(ctx_b, wkc, b_kc, kh,
      1024, 1024, 1024, 1024, 0, 0, 0);
  // ---- VT[b][d][s] = Wvc . ctx[b]^T + b_vc  (batched, K-major output, 8-phase) ----
  gemm8p<2><<<dim3(8, 4, 8), 512, 0, stream>>>(wvc, ctx_b, b_vc, vt,
      1024, 1024, 1024, 2048, 0, 2048LL * 1024, 1024LL * 2048);

  // ---- QH = lat * Wqc^T + b_qc (split-K2, writes into freed ctx region) ----
  gemm64sk<<<dim3(16, 8, 2), 256, 0, stream>>>(lat_b, wqc, partsQ, 1024, 512, 1024, 1024);
  redb_kernel<<<dim3(512), 256, 0, stream>>>(partsQ, b_qc, qhb);

  // ---- attention ----
  scores_kernel<<<dim3(8, 128), 256, 0, stream>>>(qhb, kh, cmask, probs, sums);
  pv_part_kernel<<<dim3(4, 128), 256, 0, stream>>>(probs, vt, pvp);
  pv_reduce_kernel<<<dim3(512), 256, 0, stream>>>(pvp, sums, attn_b);
  mean_kernel<<<dim3(512), 256, 0, stream>>>(probs, sums, (float*)d_out + 524288);

  // ---- out projection (split-K2) + LN1 (fused reduce + bias) ----
  gemm64sk<<<dim3(16, 8, 2), 256, 0, stream>>>(attn_b, wob, partsO, 1024, 512, 1024, 1024);
  lnp_kernel<2><<<dim3(512), 256, 0, stream>>>(latents, partsO, out_b, ln1_g, ln1_b, xf, xb);

  // ---- FF ----
  gemm64<2, 1><<<dim3(64, 8), 256, 0, stream>>>(xb, wf1b, ff_b1, h1,
      512, 4096, 1024, 1024, 1024, 4096);
  gemm64sk<<<dim3(16, 8, 4), 256, 0, stream>>>(h1, wf2b, partsF, 1024, 1024, 4096, 4096);
  lnp_kernel<4><<<dim3(512), 256, 0, stream>>>(xf, partsF, ff_b2, ln2_g, ln2_b,
                                               (float*)d_out, nullptr);
}